// Round 1
// baseline (819.400 us; speedup 1.0000x reference)
//
#include <hip/hip_runtime.h>
#include <hip/hip_bf16.h>
#include <math.h>

#define BB 2
#define TT 2048
#define CC 1024
#define NH 16
#define NKV 8
#define HD 64
#define NG 8
#define NGKV 4
#define VECH 32
#define M_ROWS (BB*TT)     // 4096
#define QKV_LD 2048

// ---------------- generic tiled f32 GEMM: C = A(MxK) @ W(KxN) ----------------
// A row-major (lda=K), W row-major (ldw), write at Cout[row*ldc + col_off + col]
__global__ __launch_bounds__(256)
void gemm_f32(const float* __restrict__ A, const float* __restrict__ W,
              float* __restrict__ Cout, int M, int N, int K,
              int ldw, int ldc, int col_off)
{
    __shared__ float As[16][64 + 4];
    __shared__ float Ws[16][64 + 4];
    const int tid = threadIdx.x;
    const int tx = tid & 15, ty = tid >> 4;
    const int bm = blockIdx.y * 64;
    const int bn = blockIdx.x * 64;
    float acc[4][4] = {};
    for (int k0 = 0; k0 < K; k0 += 16) {
        {
            int m = tid >> 2;            // 0..63
            int kq = (tid & 3) * 4;      // 0,4,8,12
            const float4 v = *reinterpret_cast<const float4*>(
                &A[(size_t)(bm + m) * K + k0 + kq]);
            As[kq + 0][m] = v.x; As[kq + 1][m] = v.y;
            As[kq + 2][m] = v.z; As[kq + 3][m] = v.w;
        }
        {
            int k = tid >> 4;            // 0..15
            int n4 = (tid & 15) * 4;
            *reinterpret_cast<float4*>(&Ws[k][n4]) =
                *reinterpret_cast<const float4*>(&W[(size_t)(k0 + k) * ldw + bn + n4]);
        }
        __syncthreads();
        #pragma unroll
        for (int k = 0; k < 16; ++k) {
            float4 a = *reinterpret_cast<const float4*>(&As[k][ty * 4]);
            float4 b = *reinterpret_cast<const float4*>(&Ws[k][tx * 4]);
            float av[4] = {a.x, a.y, a.z, a.w};
            float bv[4] = {b.x, b.y, b.z, b.w};
            #pragma unroll
            for (int i = 0; i < 4; ++i)
                #pragma unroll
                for (int j = 0; j < 4; ++j)
                    acc[i][j] = fmaf(av[i], bv[j], acc[i][j]);
        }
        __syncthreads();
    }
    #pragma unroll
    for (int i = 0; i < 4; ++i) {
        float4 o = {acc[i][0], acc[i][1], acc[i][2], acc[i][3]};
        *reinterpret_cast<float4*>(
            &Cout[(size_t)(bm + ty * 4 + i) * ldc + col_off + bn + tx * 4]) = o;
    }
}

// ---------------- gate = 2*sigmoid(x[:, :32] @ Wg) ----------------
__global__ void gate_kernel(const float* __restrict__ x, const float* __restrict__ Wg,
                            float* __restrict__ gate)
{
    int idx = blockIdx.x * blockDim.x + threadIdx.x;   // row*8 + j
    if (idx >= M_ROWS * NKV) return;
    int row = idx >> 3, j = idx & 7;
    float z = 0.f;
    #pragma unroll
    for (int i = 0; i < VECH; ++i)
        z = fmaf(x[(size_t)row * CC + i], Wg[i * NKV + j], z);
    gate[idx] = 2.0f / (1.0f + expf(-z));
}

// ---------------- rope+rms on q/k heads; v += gate*ve ----------------
__global__ __launch_bounds__(64)
void rrv_kernel(float* __restrict__ qkv, const float* __restrict__ ve,
                const float* __restrict__ gate,
                const float* __restrict__ cosb, const float* __restrict__ sinb)
{
    const int u = blockIdx.x;      // 0..31: 16 q heads, 8 k heads, 8 v heads
    const int row = blockIdx.y;    // 0..4095
    const int d = threadIdx.x;     // 0..63
    const int t = row & (TT - 1);
    if (u < 24) {
        int off = (u < 16) ? u * HD : 1024 + (u - 16) * HD;
        float v = qkv[(size_t)row * QKV_LD + off + d];
        float partner = __shfl(v, d ^ 32, 64);
        float r;
        if (d < 32) {
            float cs = cosb[t * 32 + d], sn = sinb[t * 32 + d];
            r = v * cs + partner * sn;              // x1*cos + x2*sin
        } else {
            float cs = cosb[t * 32 + (d - 32)], sn = sinb[t * 32 + (d - 32)];
            r = -partner * sn + v * cs;             // -x1*sin + x2*cos
        }
        float s = r * r;
        #pragma unroll
        for (int mm = 1; mm < 64; mm <<= 1) s += __shfl_xor(s, mm, 64);
        r *= rsqrtf(s * (1.0f / 64.0f) + 1.1920929e-07f);
        qkv[(size_t)row * QKV_LD + off + d] = r;
    } else {
        int h = u - 24;
        int off = 1536 + h * HD;
        float v = qkv[(size_t)row * QKV_LD + off + d];
        v += gate[row * NKV + h] * ve[(size_t)row * (NKV * HD) + h * HD + d];
        qkv[(size_t)row * QKV_LD + off + d] = v;
    }
}

// ---------------- flash attention, 64x64 tiles, f32 ----------------
__global__ __launch_bounds__(256)
void attn_kernel(const float* __restrict__ qkv, float* __restrict__ y,
                 const int* __restrict__ winp)
{
    __shared__ float Qs[HD][64 + 4];    // transposed [d][row], pre-scaled by 1/8
    __shared__ float KPs[64][64 + 4];   // K transposed [d][key]; later P [key][row]
    __shared__ float Vs[64][64 + 4];    // [key][d]

    const int qt = blockIdx.x;          // 0..31
    const int h  = blockIdx.y;          // 0..15
    const int b  = blockIdx.z;
    const int q0 = qt * 64;
    const int tid = threadIdx.x;
    const int tx = tid & 15, ty = tid >> 4;
    const int win = (h < NG) ? -1 : winp[0];
    const int kvh = (h < NG) ? (h >> 1) : (NGKV + ((h - NG) >> 1));
    const int qoff = h * HD;
    const int koff = 1024 + kvh * HD;
    const int voff = 1536 + kvh * HD;
    const size_t rowbase = (size_t)b * TT;

    for (int i = tid; i < 64 * 16; i += 256) {
        int r = i >> 4;
        int c4 = (i & 15) * 4;
        const float4 v = *reinterpret_cast<const float4*>(
            &qkv[(rowbase + q0 + r) * QKV_LD + qoff + c4]);
        Qs[c4 + 0][r] = v.x * 0.125f; Qs[c4 + 1][r] = v.y * 0.125f;
        Qs[c4 + 2][r] = v.z * 0.125f; Qs[c4 + 3][r] = v.w * 0.125f;
    }

    float acco[4][4] = {};
    float mrow[4], lrow[4];
    #pragma unroll
    for (int i = 0; i < 4; ++i) { mrow[i] = -1e30f; lrow[i] = 0.f; }

    int kts = 0;
    if (win >= 0) { int s = q0 - win; kts = (s > 0) ? (s >> 6) : 0; }

    for (int kt = kts; kt <= qt; ++kt) {
        __syncthreads();    // protect previous iteration's KPs/Vs reads
        for (int i = tid; i < 64 * 16; i += 256) {
            int r = i >> 4;
            int c4 = (i & 15) * 4;
            size_t g = (rowbase + kt * 64 + r) * QKV_LD;
            const float4 k4 = *reinterpret_cast<const float4*>(&qkv[g + koff + c4]);
            KPs[c4 + 0][r] = k4.x; KPs[c4 + 1][r] = k4.y;
            KPs[c4 + 2][r] = k4.z; KPs[c4 + 3][r] = k4.w;
            *reinterpret_cast<float4*>(&Vs[r][c4]) =
                *reinterpret_cast<const float4*>(&qkv[g + voff + c4]);
        }
        __syncthreads();

        float sacc[4][4] = {};
        #pragma unroll 4
        for (int d = 0; d < HD; ++d) {
            float4 a = *reinterpret_cast<const float4*>(&Qs[d][ty * 4]);
            float4 bq = *reinterpret_cast<const float4*>(&KPs[d][tx * 4]);
            float av[4] = {a.x, a.y, a.z, a.w};
            float bv[4] = {bq.x, bq.y, bq.z, bq.w};
            #pragma unroll
            for (int i = 0; i < 4; ++i)
                #pragma unroll
                for (int j = 0; j < 4; ++j)
                    sacc[i][j] = fmaf(av[i], bv[j], sacc[i][j]);
        }

        float pv[4][4];
        #pragma unroll
        for (int i = 0; i < 4; ++i) {
            int qi = q0 + ty * 4 + i;
            float rmax = -1e30f;
            #pragma unroll
            for (int j = 0; j < 4; ++j) {
                int kj = kt * 64 + tx * 4 + j;
                bool ok = (kj <= qi) && (win < 0 || (qi - kj) <= win);
                sacc[i][j] = ok ? sacc[i][j] : -1e30f;
                rmax = fmaxf(rmax, sacc[i][j]);
            }
            #pragma unroll
            for (int mm = 1; mm < 16; mm <<= 1)
                rmax = fmaxf(rmax, __shfl_xor(rmax, mm, 16));
            float mnew = fmaxf(mrow[i], rmax);
            float alpha = __expf(mrow[i] - mnew);
            float rsum = 0.f;
            #pragma unroll
            for (int j = 0; j < 4; ++j) {
                float p = (sacc[i][j] > -1e29f) ? __expf(sacc[i][j] - mnew) : 0.f;
                pv[i][j] = p; rsum += p;
            }
            #pragma unroll
            for (int mm = 1; mm < 16; mm <<= 1)
                rsum += __shfl_xor(rsum, mm, 16);
            lrow[i] = lrow[i] * alpha + rsum;
            mrow[i] = mnew;
            #pragma unroll
            for (int j = 0; j < 4; ++j) acco[i][j] *= alpha;
        }

        __syncthreads();    // done reading K from KPs
        #pragma unroll
        for (int i = 0; i < 4; ++i)
            #pragma unroll
            for (int j = 0; j < 4; ++j)
                KPs[tx * 4 + j][ty * 4 + i] = pv[i][j];
        __syncthreads();

        #pragma unroll 4
        for (int kk = 0; kk < 64; ++kk) {
            float4 p4 = *reinterpret_cast<const float4*>(&KPs[kk][ty * 4]);
            float4 v4 = *reinterpret_cast<const float4*>(&Vs[kk][tx * 4]);
            float pw[4] = {p4.x, p4.y, p4.z, p4.w};
            float vw[4] = {v4.x, v4.y, v4.z, v4.w};
            #pragma unroll
            for (int i = 0; i < 4; ++i)
                #pragma unroll
                for (int j = 0; j < 4; ++j)
                    acco[i][j] = fmaf(pw[i], vw[j], acco[i][j]);
        }
    }

    #pragma unroll
    for (int i = 0; i < 4; ++i) {
        float inv = 1.0f / lrow[i];
        float4 o = {acco[i][0] * inv, acco[i][1] * inv,
                    acco[i][2] * inv, acco[i][3] * inv};
        *reinterpret_cast<float4*>(
            &y[(rowbase + q0 + ty * 4 + i) * (size_t)CC + h * HD + tx * 4]) = o;
    }
}

extern "C" void kernel_launch(void* const* d_in, const int* in_sizes, int n_in,
                              void* d_out, int out_size, void* d_ws, size_t ws_size,
                              hipStream_t stream) {
    const float* x     = (const float*)d_in[0];
    const float* ve    = (const float*)d_in[1];
    const float* cosb  = (const float*)d_in[2];
    const float* sinb  = (const float*)d_in[3];
    const float* Wq    = (const float*)d_in[4];
    const float* Wk    = (const float*)d_in[5];
    const float* Wv    = (const float*)d_in[6];
    const float* Wproj = (const float*)d_in[7];
    const float* Wg    = (const float*)d_in[8];
    const int*   winp  = (const int*)d_in[9];

    float* qkv  = (float*)d_ws;                        // 4096 x 2048
    float* gate = qkv + (size_t)M_ROWS * QKV_LD;       // 4096 x 8
    float* ybuf = gate + (size_t)M_ROWS * NKV;         // 4096 x 1024

    dim3 blk(256);
    gemm_f32<<<dim3(1024 / 64, M_ROWS / 64), blk, 0, stream>>>(
        x, Wq, qkv, M_ROWS, 1024, CC, 1024, QKV_LD, 0);
    gemm_f32<<<dim3(512 / 64, M_ROWS / 64), blk, 0, stream>>>(
        x, Wk, qkv, M_ROWS, 512, CC, 512, QKV_LD, 1024);
    gemm_f32<<<dim3(512 / 64, M_ROWS / 64), blk, 0, stream>>>(
        x, Wv, qkv, M_ROWS, 512, CC, 512, QKV_LD, 1536);
    gate_kernel<<<(M_ROWS * NKV + 255) / 256, 256, 0, stream>>>(x, Wg, gate);
    rrv_kernel<<<dim3(32, M_ROWS), 64, 0, stream>>>(qkv, ve, gate, cosb, sinb);
    attn_kernel<<<dim3(32, 16, 2), 256, 0, stream>>>(qkv, ybuf, winp);
    gemm_f32<<<dim3(1024 / 64, M_ROWS / 64), blk, 0, stream>>>(
        ybuf, Wproj, (float*)d_out, M_ROWS, 1024, CC, 1024, 1024, 0);
}

// Round 2
// 190.157 us; speedup vs baseline: 4.3091x; 4.3091x over previous
//
#include <hip/hip_runtime.h>
#include <hip/hip_bf16.h>
#include <math.h>

typedef __bf16 bf16x8 __attribute__((ext_vector_type(8)));
typedef __bf16 bf16x4 __attribute__((ext_vector_type(4)));
typedef float  f32x4  __attribute__((ext_vector_type(4)));

#define MFMA16(a, b, c) __builtin_amdgcn_mfma_f32_16x16x32_bf16((a), (b), (c), 0, 0, 0)

__device__ __forceinline__ void gload16(const void* g, void* lds) {
    __builtin_amdgcn_global_load_lds(
        (const __attribute__((address_space(1))) uint32_t*)g,
        (__attribute__((address_space(3))) uint32_t*)lds, 16, 0, 0);
}

// ---------------------------------------------------------------------------
// cast x (f32) -> bf16, 4 elements/thread
__global__ __launch_bounds__(256)
void castx_kernel(const float* __restrict__ x, __bf16* __restrict__ xb) {
    int i = blockIdx.x * 256 + threadIdx.x;
    float4 v = reinterpret_cast<const float4*>(x)[i];
    bf16x4 o = { (__bf16)v.x, (__bf16)v.y, (__bf16)v.z, (__bf16)v.w };
    *reinterpret_cast<bf16x4*>(xb + (size_t)i * 4) = o;
}

// ---------------------------------------------------------------------------
// transpose-cast weight tile: W [K][N] f32 -> dst [N][K] bf16 (row nt_off+n)
__global__ __launch_bounds__(256)
void tw64_kernel(const float* __restrict__ W, __bf16* __restrict__ dst,
                 int N, int K, int nt_off) {
    __shared__ __bf16 Ts[64 * 72];
    const int n0 = blockIdx.x * 64, k0 = blockIdx.y * 64;
    const int tid = threadIdx.x;
    {
        int r = tid >> 2;              // k-row 0..63
        int c0 = (tid & 3) * 16;       // n-col start
        const float4* s4 = reinterpret_cast<const float4*>(
            W + (size_t)(k0 + r) * N + n0 + c0);
        float val[16];
        #pragma unroll
        for (int q = 0; q < 4; ++q) {
            float4 v = s4[q];
            val[q * 4 + 0] = v.x; val[q * 4 + 1] = v.y;
            val[q * 4 + 2] = v.z; val[q * 4 + 3] = v.w;
        }
        #pragma unroll
        for (int j = 0; j < 16; ++j) Ts[(c0 + j) * 72 + r] = (__bf16)val[j];
    }
    __syncthreads();
    {
        int n = tid >> 2, kg = (tid & 3) * 16;
        __bf16* out = dst + (size_t)(nt_off + n0 + n) * K + k0 + kg;
        bf16x8 t0 = *reinterpret_cast<const bf16x8*>(&Ts[n * 72 + kg]);
        bf16x8 t1 = *reinterpret_cast<const bf16x8*>(&Ts[n * 72 + kg + 8]);
        *reinterpret_cast<bf16x8*>(out) = t0;
        *reinterpret_cast<bf16x8*>(out + 8) = t1;
    }
}

// ---------------------------------------------------------------------------
// gate = 2*sigmoid(x[:, :32] @ Wg)   (f32, tiny)
__global__ void gate_kernel(const float* __restrict__ x, const float* __restrict__ Wg,
                            float* __restrict__ gate) {
    int idx = blockIdx.x * blockDim.x + threadIdx.x;   // row*8 + j
    if (idx >= 4096 * 8) return;
    int row = idx >> 3, j = idx & 7;
    float z = 0.f;
    #pragma unroll
    for (int i = 0; i < 32; ++i)
        z = fmaf(x[(size_t)row * 1024 + i], Wg[i * 8 + j], z);
    gate[idx] = 2.0f / (1.0f + expf(-z));
}

// ---------------------------------------------------------------------------
// bf16 MFMA GEMM: C(MxN) = A(MxK) @ Bt(NxK)^T ; 128x128 tile, BK=64, 4 waves
template <typename OutT>
__global__ __launch_bounds__(256)
void gemm_bf16(const __bf16* __restrict__ A, const __bf16* __restrict__ Bt,
               OutT* __restrict__ C, int M, int N, int K) {
    __shared__ __align__(16) __bf16 As[128 * 64];
    __shared__ __align__(16) __bf16 Bs[128 * 64];
    const int tid = threadIdx.x;
    const int lane = tid & 63, w = tid >> 6;
    const int wr = w >> 1, wc = w & 1;
    const int bm = blockIdx.y * 128, bn = blockIdx.x * 128;
    const int lhi = lane >> 4, llo = lane & 15;
    const int gsrc = (lane & 7) ^ ((lane >> 3) & 7);   // pre-swizzled source group

    f32x4 acc[4][4] = {};

    for (int k0 = 0; k0 < K; k0 += 64) {
        __syncthreads();
        const __bf16* Ab = A + (size_t)bm * K + k0;
        const __bf16* Bb = Bt + (size_t)bn * K + k0;
        #pragma unroll
        for (int rr = 0; rr < 4; ++rr) {
            int c = rr * 4 + w;
            int r = c * 8 + (lane >> 3);
            gload16(Ab + (size_t)r * K + gsrc * 8, (char*)As + c * 1024);
            gload16(Bb + (size_t)r * K + gsrc * 8, (char*)Bs + c * 1024);
        }
        __syncthreads();

        #pragma unroll
        for (int ks = 0; ks < 2; ++ks) {
            bf16x8 af[4], bfr[4];
            int g = ks * 4 + lhi;
            #pragma unroll
            for (int i = 0; i < 4; ++i) {
                int ra = wr * 64 + i * 16 + llo;
                af[i] = *reinterpret_cast<const bf16x8*>(
                    (const char*)As + ra * 128 + ((g ^ (ra & 7)) << 4));
                int rb = wc * 64 + i * 16 + llo;
                bfr[i] = *reinterpret_cast<const bf16x8*>(
                    (const char*)Bs + rb * 128 + ((g ^ (rb & 7)) << 4));
            }
            #pragma unroll
            for (int i = 0; i < 4; ++i)
                #pragma unroll
                for (int j = 0; j < 4; ++j)
                    acc[i][j] = MFMA16(af[i], bfr[j], acc[i][j]);
        }
    }

    #pragma unroll
    for (int i = 0; i < 4; ++i) {
        #pragma unroll
        for (int j = 0; j < 4; ++j) {
            int col = bn + wc * 64 + j * 16 + llo;
            #pragma unroll
            for (int r = 0; r < 4; ++r) {
                int row = bm + wr * 64 + i * 16 + lhi * 4 + r;
                C[(size_t)row * N + col] = (OutT)acc[i][j][r];
            }
        }
    }
}

// ---------------------------------------------------------------------------
// RoPE + RMS-norm on q (u<16) and k (u in 16..24) heads, bf16 in/out
__global__ __launch_bounds__(256)
void rrv_qk(__bf16* __restrict__ qkv, const float* __restrict__ cosb,
            const float* __restrict__ sinb) {
    const int u = blockIdx.x;                       // 0..23
    const int row = blockIdx.y * 4 + (threadIdx.x >> 6);
    const int d = threadIdx.x & 63;
    const int t = row & 2047;
    const int off = (u < 16) ? u * 64 : 1024 + (u - 16) * 64;
    __bf16* p = qkv + (size_t)row * 2048 + off;
    float v = (float)p[d];
    float partner = __shfl(v, d ^ 32, 64);
    float r;
    if (d < 32) {
        float cs = cosb[t * 32 + d], sn = sinb[t * 32 + d];
        r = v * cs + partner * sn;
    } else {
        float cs = cosb[t * 32 + d - 32], sn = sinb[t * 32 + d - 32];
        r = -partner * sn + v * cs;
    }
    float s = r * r;
    #pragma unroll
    for (int mm = 1; mm < 64; mm <<= 1) s += __shfl_xor(s, mm, 64);
    r *= rsqrtf(s * (1.0f / 64.0f) + 1.1920929e-07f);
    p[d] = (__bf16)r;
}

// ---------------------------------------------------------------------------
// v = v + gate*ve, then write TRANSPOSED into vT[(b*8+h)*64 + d][t] (bf16)
__global__ __launch_bounds__(256)
void vgate_t(const __bf16* __restrict__ qkv, const float* __restrict__ ve,
             const float* __restrict__ gate, __bf16* __restrict__ vT) {
    __shared__ __bf16 Ts[64 * 72];
    const int ch = blockIdx.x;      // 0..63 (row chunk of 64)
    const int h = blockIdx.y;       // 0..7
    const int tid = threadIdx.x;
    {
        int r = tid >> 2, c0 = (tid & 3) * 16;
        int grow = ch * 64 + r;
        float g = gate[grow * 8 + h];
        const __bf16* vp = qkv + (size_t)grow * 2048 + 1536 + h * 64 + c0;
        const float* vep = ve + (size_t)grow * 512 + h * 64 + c0;
        bf16x8 v0 = *reinterpret_cast<const bf16x8*>(vp);
        bf16x8 v1 = *reinterpret_cast<const bf16x8*>(vp + 8);
        #pragma unroll
        for (int j = 0; j < 8; ++j) {
            Ts[(c0 + j) * 72 + r]     = (__bf16)((float)v0[j] + g * vep[j]);
            Ts[(c0 + 8 + j) * 72 + r] = (__bf16)((float)v1[j] + g * vep[8 + j]);
        }
    }
    __syncthreads();
    {
        int d = tid >> 2, t0l = (tid & 3) * 16;
        int b = ch >> 5, tloc = (ch & 31) * 64;
        __bf16* out = vT + ((size_t)((b * 8 + h) * 64 + d)) * 2048 + tloc + t0l;
        bf16x8 t0 = *reinterpret_cast<const bf16x8*>(&Ts[d * 72 + t0l]);
        bf16x8 t1 = *reinterpret_cast<const bf16x8*>(&Ts[d * 72 + t0l + 8]);
        *reinterpret_cast<bf16x8*>(out) = t0;
        *reinterpret_cast<bf16x8*>(out + 8) = t1;
    }
}

// ---------------------------------------------------------------------------
// MFMA flash attention: Q-tile 64, KV-tile 64, 4 waves x 16 q-rows
__global__ __launch_bounds__(256)
void attn_mfma(const __bf16* __restrict__ qkv, const __bf16* __restrict__ vT,
               __bf16* __restrict__ y, const int* __restrict__ winp) {
    __shared__ __align__(16) __bf16 Qs[64 * 64];
    __shared__ __align__(16) __bf16 Ks[64 * 64];
    __shared__ __align__(16) __bf16 VTs[64 * 64];
    __shared__ __align__(16) __bf16 Ps[4][16 * 72];   // per-wave, padded

    const int qt = blockIdx.x, h = blockIdx.y, b = blockIdx.z;
    const int tid = threadIdx.x, lane = tid & 63, w = tid >> 6;
    const int q0 = qt * 64;
    const int win = (h < 8) ? -1 : winp[0];
    const int kvh = (h < 8) ? (h >> 1) : (4 + ((h - 8) >> 1));
    const int lhi = lane >> 4, llo = lane & 15;
    const int gsrc = (lane & 7) ^ ((lane >> 3) & 7);

    const __bf16* qbase = qkv + ((size_t)(b * 2048 + q0)) * 2048 + h * 64;
    const __bf16* kbase = qkv + (size_t)(b * 2048) * 2048 + 1024 + kvh * 64;
    const __bf16* vtbase = vT + ((size_t)((b * 8 + kvh) * 64)) * 2048;

    // stage Q (swizzled source)
    #pragma unroll
    for (int rr = 0; rr < 2; ++rr) {
        int c = rr * 4 + w;
        int r = c * 8 + (lane >> 3);
        gload16(qbase + (size_t)r * 2048 + gsrc * 8, (char*)Qs + c * 1024);
    }

    f32x4 oacc[4] = {};
    float mrow[4], lrow[4];
    #pragma unroll
    for (int r = 0; r < 4; ++r) { mrow[r] = -1e30f; lrow[r] = 0.f; }

    int kts = 0;
    if (win >= 0) { int s = q0 - win; kts = (s > 0) ? (s >> 6) : 0; }

    for (int kt = kts; kt <= qt; ++kt) {
        __syncthreads();
        #pragma unroll
        for (int rr = 0; rr < 2; ++rr) {
            int c = rr * 4 + w;
            int r = c * 8 + (lane >> 3);
            gload16(kbase + (size_t)(kt * 64 + r) * 2048 + gsrc * 8, (char*)Ks + c * 1024);
            gload16(vtbase + (size_t)r * 2048 + kt * 64 + gsrc * 8, (char*)VTs + c * 1024);
        }
        __syncthreads();

        // S = Q K^T for this wave's 16 q-rows
        f32x4 sacc[4] = {};
        #pragma unroll
        for (int ks = 0; ks < 2; ++ks) {
            int g = ks * 4 + lhi;
            int ra = w * 16 + llo;
            bf16x8 aq = *reinterpret_cast<const bf16x8*>(
                (const char*)Qs + ra * 128 + ((g ^ (ra & 7)) << 4));
            #pragma unroll
            for (int kj = 0; kj < 4; ++kj) {
                int rb = kj * 16 + llo;
                bf16x8 bk = *reinterpret_cast<const bf16x8*>(
                    (const char*)Ks + rb * 128 + ((g ^ (rb & 7)) << 4));
                sacc[kj] = MFMA16(aq, bk, sacc[kj]);
            }
        }

        // online softmax (per lane: 4 q-rows, 4 k-cols each)
        float pv[4][4];
        #pragma unroll
        for (int r = 0; r < 4; ++r) {
            int qrow = q0 + w * 16 + lhi * 4 + r;
            float sv[4];
            float rmax = -1e30f;
            #pragma unroll
            for (int kj = 0; kj < 4; ++kj) {
                int kidx = kt * 64 + kj * 16 + llo;
                float s = sacc[kj][r] * 0.125f;
                bool ok = (kidx <= qrow) && (win < 0 || (qrow - kidx) <= win);
                sv[kj] = ok ? s : -1e30f;
                rmax = fmaxf(rmax, sv[kj]);
            }
            #pragma unroll
            for (int mm = 1; mm < 16; mm <<= 1)
                rmax = fmaxf(rmax, __shfl_xor(rmax, mm, 64));
            float mnew = fmaxf(mrow[r], rmax);
            float alpha = __expf(mrow[r] - mnew);
            float rsum = 0.f;
            #pragma unroll
            for (int kj = 0; kj < 4; ++kj) {
                float p = __expf(sv[kj] - mnew);
                pv[r][kj] = p; rsum += p;
            }
            #pragma unroll
            for (int mm = 1; mm < 16; mm <<= 1)
                rsum += __shfl_xor(rsum, mm, 64);
            lrow[r] = lrow[r] * alpha + rsum;
            mrow[r] = mnew;
            #pragma unroll
            for (int dj = 0; dj < 4; ++dj) oacc[dj][r] *= alpha;
        }

        // P -> per-wave LDS (bf16), then PV via MFMA
        #pragma unroll
        for (int r = 0; r < 4; ++r)
            #pragma unroll
            for (int kj = 0; kj < 4; ++kj)
                Ps[w][(lhi * 4 + r) * 72 + kj * 16 + llo] = (__bf16)pv[r][kj];

        #pragma unroll
        for (int ks = 0; ks < 2; ++ks) {
            int g = ks * 4 + lhi;
            bf16x8 ap = *reinterpret_cast<const bf16x8*>(
                (const char*)&Ps[w][0] + llo * 144 + g * 16);
            #pragma unroll
            for (int dj = 0; dj < 4; ++dj) {
                int rv = dj * 16 + llo;
                bf16x8 bv = *reinterpret_cast<const bf16x8*>(
                    (const char*)VTs + rv * 128 + ((g ^ (rv & 7)) << 4));
                oacc[dj] = MFMA16(ap, bv, oacc[dj]);
            }
        }
    }

    #pragma unroll
    for (int r = 0; r < 4; ++r) {
        float inv = 1.0f / lrow[r];
        int row = b * 2048 + q0 + w * 16 + lhi * 4 + r;
        #pragma unroll
        for (int dj = 0; dj < 4; ++dj)
            y[(size_t)row * 1024 + h * 64 + dj * 16 + llo] =
                (__bf16)(oacc[dj][r] * inv);
    }
}

// ---------------------------------------------------------------------------
extern "C" void kernel_launch(void* const* d_in, const int* in_sizes, int n_in,
                              void* d_out, int out_size, void* d_ws, size_t ws_size,
                              hipStream_t stream) {
    const float* x     = (const float*)d_in[0];
    const float* ve    = (const float*)d_in[1];
    const float* cosb  = (const float*)d_in[2];
    const float* sinb  = (const float*)d_in[3];
    const float* Wq    = (const float*)d_in[4];
    const float* Wk    = (const float*)d_in[5];
    const float* Wv    = (const float*)d_in[6];
    const float* Wproj = (const float*)d_in[7];
    const float* Wg    = (const float*)d_in[8];
    const int*   winp  = (const int*)d_in[9];

    char* ws = (char*)d_ws;
    __bf16* qkv    = (__bf16*)(ws);                       // 16 MB  [4096][2048]
    __bf16* vT     = (__bf16*)(ws + (16u << 20));         //  4 MB  [2*8*64][2048]
    __bf16* ybuf   = (__bf16*)(ws + (20u << 20));         //  8 MB  [4096][1024]
    __bf16* xb     = (__bf16*)(ws + (28u << 20));         //  8 MB  [4096][1024]
    __bf16* wqkvt  = (__bf16*)(ws + (36u << 20));         //  4 MB  [2048][1024]
    __bf16* wprojt = (__bf16*)(ws + (40u << 20));         //  2 MB  [1024][1024]
    float*  gate   = (float*) (ws + (42u << 20));         // 128 KB [4096][8]

    castx_kernel<<<4096, 256, 0, stream>>>(x, xb);
    tw64_kernel<<<dim3(16, 16), 256, 0, stream>>>(Wq, wqkvt, 1024, 1024, 0);
    tw64_kernel<<<dim3(8, 16), 256, 0, stream>>>(Wk, wqkvt, 512, 1024, 1024);
    tw64_kernel<<<dim3(8, 16), 256, 0, stream>>>(Wv, wqkvt, 512, 1024, 1536);
    tw64_kernel<<<dim3(16, 16), 256, 0, stream>>>(Wproj, wprojt, 1024, 1024, 0);
    gate_kernel<<<128, 256, 0, stream>>>(x, Wg, gate);

    gemm_bf16<__bf16><<<dim3(16, 32), 256, 0, stream>>>(xb, wqkvt, qkv, 4096, 2048, 1024);
    rrv_qk<<<dim3(24, 1024), 256, 0, stream>>>(qkv, cosb, sinb);
    vgate_t<<<dim3(64, 8), 256, 0, stream>>>(qkv, ve, gate, vT);
    attn_mfma<<<dim3(32, 16, 2), 256, 0, stream>>>(qkv, vT, ybuf, winp);
    gemm_bf16<float><<<dim3(8, 32), 256, 0, stream>>>(ybuf, wprojt, (float*)d_out, 4096, 1024, 1024);
}

// Round 3
// 152.618 us; speedup vs baseline: 5.3690x; 1.2460x over previous
//
#include <hip/hip_runtime.h>
#include <hip/hip_bf16.h>
#include <math.h>

typedef __bf16 bf16x8 __attribute__((ext_vector_type(8)));
typedef __bf16 bf16x4 __attribute__((ext_vector_type(4)));
typedef float  f32x4  __attribute__((ext_vector_type(4)));

#define MFMA16(a, b, c) __builtin_amdgcn_mfma_f32_16x16x32_bf16((a), (b), (c), 0, 0, 0)

__device__ __forceinline__ void gload16(const void* g, void* lds) {
    __builtin_amdgcn_global_load_lds(
        (const __attribute__((address_space(1))) uint32_t*)g,
        (__attribute__((address_space(3))) uint32_t*)lds, 16, 0, 0);
}

// ---------------------------------------------------------------------------
// cast x (f32) -> bf16, 4 elements/thread
__global__ __launch_bounds__(256)
void castx_kernel(const float* __restrict__ x, __bf16* __restrict__ xb) {
    int i = blockIdx.x * 256 + threadIdx.x;
    float4 v = reinterpret_cast<const float4*>(x)[i];
    bf16x4 o = { (__bf16)v.x, (__bf16)v.y, (__bf16)v.z, (__bf16)v.w };
    *reinterpret_cast<bf16x4*>(xb + (size_t)i * 4) = o;
}

// ---------------------------------------------------------------------------
// transpose-cast weight tile: W [K][N] f32 -> dst [N][K] bf16 (row nt_off+n)
__global__ __launch_bounds__(256)
void tw64_kernel(const float* __restrict__ W, __bf16* __restrict__ dst,
                 int N, int K, int nt_off) {
    __shared__ __bf16 Ts[64 * 72];
    const int n0 = blockIdx.x * 64, k0 = blockIdx.y * 64;
    const int tid = threadIdx.x;
    {
        int r = tid >> 2;              // k-row 0..63
        int c0 = (tid & 3) * 16;       // n-col start
        const float4* s4 = reinterpret_cast<const float4*>(
            W + (size_t)(k0 + r) * N + n0 + c0);
        float val[16];
        #pragma unroll
        for (int q = 0; q < 4; ++q) {
            float4 v = s4[q];
            val[q * 4 + 0] = v.x; val[q * 4 + 1] = v.y;
            val[q * 4 + 2] = v.z; val[q * 4 + 3] = v.w;
        }
        #pragma unroll
        for (int j = 0; j < 16; ++j) Ts[(c0 + j) * 72 + r] = (__bf16)val[j];
    }
    __syncthreads();
    {
        int n = tid >> 2, kg = (tid & 3) * 16;
        __bf16* out = dst + (size_t)(nt_off + n0 + n) * K + k0 + kg;
        bf16x8 t0 = *reinterpret_cast<const bf16x8*>(&Ts[n * 72 + kg]);
        bf16x8 t1 = *reinterpret_cast<const bf16x8*>(&Ts[n * 72 + kg + 8]);
        *reinterpret_cast<bf16x8*>(out) = t0;
        *reinterpret_cast<bf16x8*>(out + 8) = t1;
    }
}

// ---------------------------------------------------------------------------
// gate = 2*sigmoid(x[:, :32] @ Wg)   (f32, tiny)
__global__ void gate_kernel(const float* __restrict__ x, const float* __restrict__ Wg,
                            float* __restrict__ gate) {
    int idx = blockIdx.x * blockDim.x + threadIdx.x;   // row*8 + j
    if (idx >= 4096 * 8) return;
    int row = idx >> 3, j = idx & 7;
    float z = 0.f;
    #pragma unroll
    for (int i = 0; i < 32; ++i)
        z = fmaf(x[(size_t)row * 1024 + i], Wg[i * 8 + j], z);
    gate[idx] = 2.0f / (1.0f + expf(-z));
}

// ---------------------------------------------------------------------------
// bf16 MFMA GEMM: C(MxN) = A(MxK) @ Bt(NxK)^T ; 128x128 tile, BK=64, 4 waves
template <typename OutT>
__global__ __launch_bounds__(256)
void gemm_bf16(const __bf16* __restrict__ A, const __bf16* __restrict__ Bt,
               OutT* __restrict__ C, int M, int N, int K) {
    __shared__ __align__(16) __bf16 As[128 * 64];
    __shared__ __align__(16) __bf16 Bs[128 * 64];
    const int tid = threadIdx.x;
    const int lane = tid & 63, w = tid >> 6;
    const int wr = w >> 1, wc = w & 1;
    const int bm = blockIdx.y * 128, bn = blockIdx.x * 128;
    const int lhi = lane >> 4, llo = lane & 15;
    const int gsrc = (lane & 7) ^ ((lane >> 3) & 7);   // pre-swizzled source group

    f32x4 acc[4][4] = {};

    for (int k0 = 0; k0 < K; k0 += 64) {
        __syncthreads();
        const __bf16* Ab = A + (size_t)bm * K + k0;
        const __bf16* Bb = Bt + (size_t)bn * K + k0;
        #pragma unroll
        for (int rr = 0; rr < 4; ++rr) {
            int c = rr * 4 + w;
            int r = c * 8 + (lane >> 3);
            gload16(Ab + (size_t)r * K + gsrc * 8, (char*)As + c * 1024);
            gload16(Bb + (size_t)r * K + gsrc * 8, (char*)Bs + c * 1024);
        }
        __syncthreads();

        #pragma unroll
        for (int ks = 0; ks < 2; ++ks) {
            bf16x8 af[4], bfr[4];
            int g = ks * 4 + lhi;
            #pragma unroll
            for (int i = 0; i < 4; ++i) {
                int ra = wr * 64 + i * 16 + llo;
                af[i] = *reinterpret_cast<const bf16x8*>(
                    (const char*)As + ra * 128 + ((g ^ (ra & 7)) << 4));
                int rb = wc * 64 + i * 16 + llo;
                bfr[i] = *reinterpret_cast<const bf16x8*>(
                    (const char*)Bs + rb * 128 + ((g ^ (rb & 7)) << 4));
            }
            #pragma unroll
            for (int i = 0; i < 4; ++i)
                #pragma unroll
                for (int j = 0; j < 4; ++j)
                    acc[i][j] = MFMA16(af[i], bfr[j], acc[i][j]);
        }
    }

    #pragma unroll
    for (int i = 0; i < 4; ++i) {
        #pragma unroll
        for (int j = 0; j < 4; ++j) {
            int col = bn + wc * 64 + j * 16 + llo;
            #pragma unroll
            for (int r = 0; r < 4; ++r) {
                int row = bm + wr * 64 + i * 16 + lhi * 4 + r;
                C[(size_t)row * N + col] = (OutT)acc[i][j][r];
            }
        }
    }
}

// ---------------------------------------------------------------------------
// RoPE + RMS-norm on q (u<16) and k (u in 16..24) heads, bf16 in/out.
// Q heads additionally scaled by 0.125*log2(e) so attention softmax runs in
// exp2 domain with no per-score multiply.
__global__ __launch_bounds__(256)
void rrv_qk(__bf16* __restrict__ qkv, const float* __restrict__ cosb,
            const float* __restrict__ sinb) {
    const int u = blockIdx.x;                       // 0..23
    const int row = blockIdx.y * 4 + (threadIdx.x >> 6);
    const int d = threadIdx.x & 63;
    const int t = row & 2047;
    const int off = (u < 16) ? u * 64 : 1024 + (u - 16) * 64;
    __bf16* p = qkv + (size_t)row * 2048 + off;
    float v = (float)p[d];
    float partner = __shfl(v, d ^ 32, 64);
    float r;
    if (d < 32) {
        float cs = cosb[t * 32 + d], sn = sinb[t * 32 + d];
        r = v * cs + partner * sn;
    } else {
        float cs = cosb[t * 32 + d - 32], sn = sinb[t * 32 + d - 32];
        r = -partner * sn + v * cs;
    }
    float s = r * r;
    #pragma unroll
    for (int mm = 1; mm < 64; mm <<= 1) s += __shfl_xor(s, mm, 64);
    r *= rsqrtf(s * (1.0f / 64.0f) + 1.1920929e-07f);
    if (u < 16) r *= 0.18033688011116012f;          // 0.125 * log2(e)
    p[d] = (__bf16)r;
}

// ---------------------------------------------------------------------------
// v = v + gate*ve, then write TRANSPOSED into vT[(b*8+h)*64 + d][t] (bf16)
__global__ __launch_bounds__(256)
void vgate_t(const __bf16* __restrict__ qkv, const float* __restrict__ ve,
             const float* __restrict__ gate, __bf16* __restrict__ vT) {
    __shared__ __bf16 Ts[64 * 72];
    const int ch = blockIdx.x;      // 0..63 (row chunk of 64)
    const int h = blockIdx.y;       // 0..7
    const int tid = threadIdx.x;
    {
        int r = tid >> 2, c0 = (tid & 3) * 16;
        int grow = ch * 64 + r;
        float g = gate[grow * 8 + h];
        const __bf16* vp = qkv + (size_t)grow * 2048 + 1536 + h * 64 + c0;
        const float* vep = ve + (size_t)grow * 512 + h * 64 + c0;
        bf16x8 v0 = *reinterpret_cast<const bf16x8*>(vp);
        bf16x8 v1 = *reinterpret_cast<const bf16x8*>(vp + 8);
        #pragma unroll
        for (int j = 0; j < 8; ++j) {
            Ts[(c0 + j) * 72 + r]     = (__bf16)((float)v0[j] + g * vep[j]);
            Ts[(c0 + 8 + j) * 72 + r] = (__bf16)((float)v1[j] + g * vep[8 + j]);
        }
    }
    __syncthreads();
    {
        int d = tid >> 2, t0l = (tid & 3) * 16;
        int b = ch >> 5, tloc = (ch & 31) * 64;
        __bf16* out = vT + ((size_t)((b * 8 + h) * 64 + d)) * 2048 + tloc + t0l;
        bf16x8 t0 = *reinterpret_cast<const bf16x8*>(&Ts[d * 72 + t0l]);
        bf16x8 t1 = *reinterpret_cast<const bf16x8*>(&Ts[d * 72 + t0l + 8]);
        *reinterpret_cast<bf16x8*>(out) = t0;
        *reinterpret_cast<bf16x8*>(out + 8) = t1;
    }
}

// ---------------------------------------------------------------------------
// MFMA flash attention v2: QBLK=128 (4 waves x 32 q-rows), KVBLK=64,
// Q in registers, S^T-swapped MFMA (lane-local softmax rows), transposed O
// accumulator, double-buffered K/V with single barrier per tile.
__global__ __launch_bounds__(256)
void attn_mfma(const __bf16* __restrict__ qkv, const __bf16* __restrict__ vT,
               __bf16* __restrict__ y, const int* __restrict__ winp) {
    __shared__ __align__(16) __bf16 Ks[2][64 * 64];
    __shared__ __align__(16) __bf16 VTs[2][64 * 64];
    __shared__ __align__(16) __bf16 Ps[4][32 * 72];

    const int bx = blockIdx.x;
    const int h = bx & 15, b = bx >> 4;
    const int yq = blockIdx.y;
    const int qt = (yq < 8) ? yq : 23 - yq;     // complementary pairing: balanced CUs
    const int q0 = qt * 128;
    const int tid = threadIdx.x, lane = tid & 63, w = tid >> 6;
    const int lhi = lane >> 4, llo = lane & 15;
    const int gsrc = (lane & 7) ^ ((lane >> 3) & 7);
    const int win = (h < 8) ? -1 : winp[0];
    const int winv = (win < 0) ? (1 << 30) : win;
    const int kvh = (h < 8) ? (h >> 1) : (4 + ((h - 8) >> 1));

    const __bf16* kbase = qkv + (size_t)(b * 2048) * 2048 + 1024 + kvh * 64;
    const __bf16* vtbase = vT + ((size_t)((b * 8 + kvh) * 64)) * 2048;

    int kts = 0;
    if (win >= 0) { int s = q0 - win; if (s > 0) kts = s >> 6; }
    const int ktend = 2 * qt + 1;

    // Q fragments held in registers: qf[mi][ks], lane row = q0+w*32+mi*16+llo
    const __bf16* qrow = qkv + (size_t)(b * 2048 + q0 + w * 32 + llo) * 2048
                         + h * 64 + lhi * 8;
    bf16x8 qf[2][2];
    qf[0][0] = *(const bf16x8*)(qrow);
    qf[0][1] = *(const bf16x8*)(qrow + 32);
    qf[1][0] = *(const bf16x8*)(qrow + 16 * 2048);
    qf[1][1] = *(const bf16x8*)(qrow + 16 * 2048 + 32);

    auto STAGE = [&](int buf, int ktx) {
        #pragma unroll
        for (int rr = 0; rr < 2; ++rr) {
            int c = rr * 4 + w;
            int r = c * 8 + (lane >> 3);
            gload16(kbase + (size_t)(ktx * 64 + r) * 2048 + gsrc * 8,
                    (char*)&Ks[buf][0] + c * 1024);
            gload16(vtbase + (size_t)r * 2048 + ktx * 64 + gsrc * 8,
                    (char*)&VTs[buf][0] + c * 1024);
        }
    };

    f32x4 oaccT[2][4] = {};
    float mrow[2] = {-1e30f, -1e30f};
    float lrow[2] = {0.f, 0.f};
    int cur = 0;
    STAGE(0, kts);

    for (int kt = kts; kt <= ktend; ++kt) {
        __syncthreads();                         // cur data visible; prev reads done
        if (kt < ktend) STAGE(cur ^ 1, kt + 1);  // async, lands during compute

        // ---- S^T = K · Q^T : sacc[mi][kj], D[key][q] with q = llo ----
        bf16x8 bk[4][2];
        #pragma unroll
        for (int kj = 0; kj < 4; ++kj) {
            int rb = kj * 16 + llo;
            #pragma unroll
            for (int ks = 0; ks < 2; ++ks)
                bk[kj][ks] = *(const bf16x8*)((const char*)&Ks[cur][0]
                    + rb * 128 + (((ks * 4 + lhi) ^ (rb & 7)) << 4));
        }
        f32x4 sacc[2][4] = {};
        #pragma unroll
        for (int ks = 0; ks < 2; ++ks)
            #pragma unroll
            for (int mi = 0; mi < 2; ++mi)
                #pragma unroll
                for (int kj = 0; kj < 4; ++kj)
                    sacc[mi][kj] = MFMA16(bk[kj][ks], qf[mi][ks], sacc[mi][kj]);

        const bool needMask = (kt >= 2 * qt) || (kt * 64 < q0 + 127 - winv);

        #pragma unroll
        for (int mi = 0; mi < 2; ++mi) {
            float sv[16];
            #pragma unroll
            for (int kj = 0; kj < 4; ++kj)
                #pragma unroll
                for (int r = 0; r < 4; ++r)
                    sv[kj * 4 + r] = sacc[mi][kj][r];
            if (needMask) {
                int qrowi = q0 + w * 32 + mi * 16 + llo;
                #pragma unroll
                for (int kj = 0; kj < 4; ++kj)
                    #pragma unroll
                    for (int r = 0; r < 4; ++r) {
                        int key = kt * 64 + kj * 16 + lhi * 4 + r;
                        bool ok = (key <= qrowi) && (qrowi - key <= winv);
                        if (!ok) sv[kj * 4 + r] = -1e30f;
                    }
            }
            // lane-local row reduction (q = llo): 15 fmax + 2 shfl
            float rm = sv[0];
            #pragma unroll
            for (int t = 1; t < 16; ++t) rm = fmaxf(rm, sv[t]);
            rm = fmaxf(rm, __shfl_xor(rm, 16, 64));
            rm = fmaxf(rm, __shfl_xor(rm, 32, 64));
            float mnew = fmaxf(mrow[mi], rm);
            float alpha = __builtin_amdgcn_exp2f(mrow[mi] - mnew);
            float p[16], rs = 0.f;
            #pragma unroll
            for (int t = 0; t < 16; ++t) {
                p[t] = __builtin_amdgcn_exp2f(sv[t] - mnew);
                rs += p[t];
            }
            rs += __shfl_xor(rs, 16, 64);
            rs += __shfl_xor(rs, 32, 64);
            lrow[mi] = lrow[mi] * alpha + rs;
            mrow[mi] = mnew;
            #pragma unroll
            for (int dj = 0; dj < 4; ++dj) oaccT[mi][dj] *= alpha;
            // packed P write: keys kj*16+lhi*4..+3 contiguous -> b64
            #pragma unroll
            for (int kj = 0; kj < 4; ++kj) {
                bf16x4 pk = { (__bf16)p[kj * 4 + 0], (__bf16)p[kj * 4 + 1],
                              (__bf16)p[kj * 4 + 2], (__bf16)p[kj * 4 + 3] };
                *(bf16x4*)((char*)&Ps[w][0] + (mi * 16 + llo) * 144
                           + kj * 32 + lhi * 8) = pk;
            }
        }

        // ---- O^T += V^T · P^T : oaccT[mi][dj], D[d][q] with q = llo ----
        #pragma unroll
        for (int ks = 0; ks < 2; ++ks) {
            bf16x8 ap[2];
            #pragma unroll
            for (int mi = 0; mi < 2; ++mi)
                ap[mi] = *(const bf16x8*)((const char*)&Ps[w][0]
                    + (mi * 16 + llo) * 144 + ks * 64 + lhi * 16);
            #pragma unroll
            for (int dj = 0; dj < 4; ++dj) {
                int rv = dj * 16 + llo;
                bf16x8 bv = *(const bf16x8*)((const char*)&VTs[cur][0]
                    + rv * 128 + (((ks * 4 + lhi) ^ (rv & 7)) << 4));
                #pragma unroll
                for (int mi = 0; mi < 2; ++mi)
                    oaccT[mi][dj] = MFMA16(bv, ap[mi], oaccT[mi][dj]);
            }
        }
        cur ^= 1;
    }

    #pragma unroll
    for (int mi = 0; mi < 2; ++mi) {
        float inv = 1.0f / lrow[mi];
        int row = b * 2048 + q0 + w * 32 + mi * 16 + llo;
        #pragma unroll
        for (int dj = 0; dj < 4; ++dj) {
            bf16x4 o = { (__bf16)(oaccT[mi][dj][0] * inv),
                         (__bf16)(oaccT[mi][dj][1] * inv),
                         (__bf16)(oaccT[mi][dj][2] * inv),
                         (__bf16)(oaccT[mi][dj][3] * inv) };
            *(bf16x4*)(&y[(size_t)row * 1024 + h * 64 + dj * 16 + lhi * 4]) = o;
        }
    }
}

// ---------------------------------------------------------------------------
extern "C" void kernel_launch(void* const* d_in, const int* in_sizes, int n_in,
                              void* d_out, int out_size, void* d_ws, size_t ws_size,
                              hipStream_t stream) {
    const float* x     = (const float*)d_in[0];
    const float* ve    = (const float*)d_in[1];
    const float* cosb  = (const float*)d_in[2];
    const float* sinb  = (const float*)d_in[3];
    const float* Wq    = (const float*)d_in[4];
    const float* Wk    = (const float*)d_in[5];
    const float* Wv    = (const float*)d_in[6];
    const float* Wproj = (const float*)d_in[7];
    const float* Wg    = (const float*)d_in[8];
    const int*   winp  = (const int*)d_in[9];

    char* ws = (char*)d_ws;
    __bf16* qkv    = (__bf16*)(ws);                       // 16 MB  [4096][2048]
    __bf16* vT     = (__bf16*)(ws + (16u << 20));         //  4 MB  [2*8*64][2048]
    __bf16* ybuf   = (__bf16*)(ws + (20u << 20));         //  8 MB  [4096][1024]
    __bf16* xb     = (__bf16*)(ws + (28u << 20));         //  8 MB  [4096][1024]
    __bf16* wqkvt  = (__bf16*)(ws + (36u << 20));         //  4 MB  [2048][1024]
    __bf16* wprojt = (__bf16*)(ws + (40u << 20));         //  2 MB  [1024][1024]
    float*  gate   = (float*) (ws + (42u << 20));         // 128 KB [4096][8]

    castx_kernel<<<4096, 256, 0, stream>>>(x, xb);
    tw64_kernel<<<dim3(16, 16), 256, 0, stream>>>(Wq, wqkvt, 1024, 1024, 0);
    tw64_kernel<<<dim3(8, 16), 256, 0, stream>>>(Wk, wqkvt, 512, 1024, 1024);
    tw64_kernel<<<dim3(8, 16), 256, 0, stream>>>(Wv, wqkvt, 512, 1024, 1536);
    tw64_kernel<<<dim3(16, 16), 256, 0, stream>>>(Wproj, wprojt, 1024, 1024, 0);
    gate_kernel<<<128, 256, 0, stream>>>(x, Wg, gate);

    gemm_bf16<__bf16><<<dim3(16, 32), 256, 0, stream>>>(xb, wqkvt, qkv, 4096, 2048, 1024);
    rrv_qk<<<dim3(24, 1024), 256, 0, stream>>>(qkv, cosb, sinb);
    vgate_t<<<dim3(64, 8), 256, 0, stream>>>(qkv, ve, gate, vT);
    attn_mfma<<<dim3(32, 16), 256, 0, stream>>>(qkv, vT, ybuf, winp);
    gemm_bf16<float><<<dim3(8, 32), 256, 0, stream>>>(ybuf, wprojt, (float*)d_out, 4096, 1024, 1024);
}

// Round 4
// 132.719 us; speedup vs baseline: 6.1739x; 1.1499x over previous
//
#include <hip/hip_runtime.h>
#include <hip/hip_bf16.h>
#include <math.h>

typedef __bf16 bf16x8 __attribute__((ext_vector_type(8)));
typedef __bf16 bf16x4 __attribute__((ext_vector_type(4)));
typedef float  f32x4  __attribute__((ext_vector_type(4)));

#define MFMA16(a, b, c) __builtin_amdgcn_mfma_f32_16x16x32_bf16((a), (b), (c), 0, 0, 0)

__device__ __forceinline__ void gload16(const void* g, void* lds) {
    __builtin_amdgcn_global_load_lds(
        (const __attribute__((address_space(1))) uint32_t*)g,
        (__attribute__((address_space(3))) uint32_t*)lds, 16, 0, 0);
}

// ---------------------------------------------------------------------------
// cast x (f32) -> bf16, 4 elements/thread
__global__ __launch_bounds__(256)
void castx_kernel(const float* __restrict__ x, __bf16* __restrict__ xb) {
    int i = blockIdx.x * 256 + threadIdx.x;
    float4 v = reinterpret_cast<const float4*>(x)[i];
    bf16x4 o = { (__bf16)v.x, (__bf16)v.y, (__bf16)v.z, (__bf16)v.w };
    *reinterpret_cast<bf16x4*>(xb + (size_t)i * 4) = o;
}

// ---------------------------------------------------------------------------
// transpose-cast weight tile: W [K][N] f32 -> dst [N][K] bf16 (row nt_off+n)
__global__ __launch_bounds__(256)
void tw64_kernel(const float* __restrict__ W, __bf16* __restrict__ dst,
                 int N, int K, int nt_off) {
    __shared__ __bf16 Ts[64 * 72];
    const int n0 = blockIdx.x * 64, k0 = blockIdx.y * 64;
    const int tid = threadIdx.x;
    {
        int r = tid >> 2;              // k-row 0..63
        int c0 = (tid & 3) * 16;       // n-col start
        const float4* s4 = reinterpret_cast<const float4*>(
            W + (size_t)(k0 + r) * N + n0 + c0);
        float val[16];
        #pragma unroll
        for (int q = 0; q < 4; ++q) {
            float4 v = s4[q];
            val[q * 4 + 0] = v.x; val[q * 4 + 1] = v.y;
            val[q * 4 + 2] = v.z; val[q * 4 + 3] = v.w;
        }
        #pragma unroll
        for (int j = 0; j < 16; ++j) Ts[(c0 + j) * 72 + r] = (__bf16)val[j];
    }
    __syncthreads();
    {
        int n = tid >> 2, kg = (tid & 3) * 16;
        __bf16* out = dst + (size_t)(nt_off + n0 + n) * K + k0 + kg;
        bf16x8 t0 = *reinterpret_cast<const bf16x8*>(&Ts[n * 72 + kg]);
        bf16x8 t1 = *reinterpret_cast<const bf16x8*>(&Ts[n * 72 + kg + 8]);
        *reinterpret_cast<bf16x8*>(out) = t0;
        *reinterpret_cast<bf16x8*>(out + 8) = t1;
    }
}

// ---------------------------------------------------------------------------
// gate = 2*sigmoid(x[:, :32] @ Wg)   (f32, tiny)
__global__ void gate_kernel(const float* __restrict__ x, const float* __restrict__ Wg,
                            float* __restrict__ gate) {
    int idx = blockIdx.x * blockDim.x + threadIdx.x;   // row*8 + j
    if (idx >= 4096 * 8) return;
    int row = idx >> 3, j = idx & 7;
    float z = 0.f;
    #pragma unroll
    for (int i = 0; i < 32; ++i)
        z = fmaf(x[(size_t)row * 1024 + i], Wg[i * 8 + j], z);
    gate[idx] = 2.0f / (1.0f + expf(-z));
}

// ---------------------------------------------------------------------------
// bf16 MFMA GEMM: C(MxN) = A(MxK) @ Bt(NxK)^T ; 128x128 tile, BK=64, 4 waves
template <typename OutT>
__global__ __launch_bounds__(256)
void gemm_bf16(const __bf16* __restrict__ A, const __bf16* __restrict__ Bt,
               OutT* __restrict__ C, int M, int N, int K) {
    __shared__ __align__(16) __bf16 As[128 * 64];
    __shared__ __align__(16) __bf16 Bs[128 * 64];
    const int tid = threadIdx.x;
    const int lane = tid & 63, w = tid >> 6;
    const int wr = w >> 1, wc = w & 1;
    const int bm = blockIdx.y * 128, bn = blockIdx.x * 128;
    const int lhi = lane >> 4, llo = lane & 15;
    const int gsrc = (lane & 7) ^ ((lane >> 3) & 7);   // pre-swizzled source group

    f32x4 acc[4][4] = {};

    for (int k0 = 0; k0 < K; k0 += 64) {
        __syncthreads();
        const __bf16* Ab = A + (size_t)bm * K + k0;
        const __bf16* Bb = Bt + (size_t)bn * K + k0;
        #pragma unroll
        for (int rr = 0; rr < 4; ++rr) {
            int c = rr * 4 + w;
            int r = c * 8 + (lane >> 3);
            gload16(Ab + (size_t)r * K + gsrc * 8, (char*)As + c * 1024);
            gload16(Bb + (size_t)r * K + gsrc * 8, (char*)Bs + c * 1024);
        }
        __syncthreads();

        #pragma unroll
        for (int ks = 0; ks < 2; ++ks) {
            bf16x8 af[4], bfr[4];
            int g = ks * 4 + lhi;
            #pragma unroll
            for (int i = 0; i < 4; ++i) {
                int ra = wr * 64 + i * 16 + llo;
                af[i] = *reinterpret_cast<const bf16x8*>(
                    (const char*)As + ra * 128 + ((g ^ (ra & 7)) << 4));
                int rb = wc * 64 + i * 16 + llo;
                bfr[i] = *reinterpret_cast<const bf16x8*>(
                    (const char*)Bs + rb * 128 + ((g ^ (rb & 7)) << 4));
            }
            #pragma unroll
            for (int i = 0; i < 4; ++i)
                #pragma unroll
                for (int j = 0; j < 4; ++j)
                    acc[i][j] = MFMA16(af[i], bfr[j], acc[i][j]);
        }
    }

    #pragma unroll
    for (int i = 0; i < 4; ++i) {
        #pragma unroll
        for (int j = 0; j < 4; ++j) {
            int col = bn + wc * 64 + j * 16 + llo;
            #pragma unroll
            for (int r = 0; r < 4; ++r) {
                int row = bm + wr * 64 + i * 16 + lhi * 4 + r;
                C[(size_t)row * N + col] = (OutT)acc[i][j][r];
            }
        }
    }
}

// ---------------------------------------------------------------------------
// RoPE + RMS-norm on q (u<16) and k (u in 16..24) heads, bf16 in/out.
// Q heads additionally scaled by 0.125*log2(e) (exp2-domain softmax).
__global__ __launch_bounds__(256)
void rrv_qk(__bf16* __restrict__ qkv, const float* __restrict__ cosb,
            const float* __restrict__ sinb) {
    const int u = blockIdx.x;                       // 0..23
    const int row = blockIdx.y * 4 + (threadIdx.x >> 6);
    const int d = threadIdx.x & 63;
    const int t = row & 2047;
    const int off = (u < 16) ? u * 64 : 1024 + (u - 16) * 64;
    __bf16* p = qkv + (size_t)row * 2048 + off;
    float v = (float)p[d];
    float partner = __shfl(v, d ^ 32, 64);
    float r;
    if (d < 32) {
        float cs = cosb[t * 32 + d], sn = sinb[t * 32 + d];
        r = v * cs + partner * sn;
    } else {
        float cs = cosb[t * 32 + d - 32], sn = sinb[t * 32 + d - 32];
        r = -partner * sn + v * cs;
    }
    float s = r * r;
    #pragma unroll
    for (int mm = 1; mm < 64; mm <<= 1) s += __shfl_xor(s, mm, 64);
    r *= rsqrtf(s * (1.0f / 64.0f) + 1.1920929e-07f);
    if (u < 16) r *= 0.18033688011116012f;          // 0.125 * log2(e)
    p[d] = (__bf16)r;
}

// ---------------------------------------------------------------------------
// v = v + gate*ve, then write TRANSPOSED into vT[(b*8+h)*64 + d][t] (bf16)
__global__ __launch_bounds__(256)
void vgate_t(const __bf16* __restrict__ qkv, const float* __restrict__ ve,
             const float* __restrict__ gate, __bf16* __restrict__ vT) {
    __shared__ __bf16 Ts[64 * 72];
    const int ch = blockIdx.x;      // 0..63 (row chunk of 64)
    const int h = blockIdx.y;       // 0..7
    const int tid = threadIdx.x;
    {
        int r = tid >> 2, c0 = (tid & 3) * 16;
        int grow = ch * 64 + r;
        float g = gate[grow * 8 + h];
        const __bf16* vp = qkv + (size_t)grow * 2048 + 1536 + h * 64 + c0;
        const float* vep = ve + (size_t)grow * 512 + h * 64 + c0;
        bf16x8 v0 = *reinterpret_cast<const bf16x8*>(vp);
        bf16x8 v1 = *reinterpret_cast<const bf16x8*>(vp + 8);
        #pragma unroll
        for (int j = 0; j < 8; ++j) {
            Ts[(c0 + j) * 72 + r]     = (__bf16)((float)v0[j] + g * vep[j]);
            Ts[(c0 + 8 + j) * 72 + r] = (__bf16)((float)v1[j] + g * vep[8 + j]);
        }
    }
    __syncthreads();
    {
        int d = tid >> 2, t0l = (tid & 3) * 16;
        int b = ch >> 5, tloc = (ch & 31) * 64;
        __bf16* out = vT + ((size_t)((b * 8 + h) * 64 + d)) * 2048 + tloc + t0l;
        bf16x8 t0 = *reinterpret_cast<const bf16x8*>(&Ts[d * 72 + t0l]);
        bf16x8 t1 = *reinterpret_cast<const bf16x8*>(&Ts[d * 72 + t0l + 8]);
        *reinterpret_cast<bf16x8*>(out) = t0;
        *reinterpret_cast<bf16x8*>(out + 8) = t1;
    }
}

// ---------------------------------------------------------------------------
// MFMA flash attention v3: QBLK=64 (4 waves x 16 q-rows), KVBLK=64,
// grid 1024 blocks (4/CU, LDS exactly 40960B), balanced qt striping,
// Q in registers, swapped-S^T MFMA, XOR-swizzled per-wave P, defer-max.
__global__ __launch_bounds__(256, 4)
void attn_mfma(const __bf16* __restrict__ qkv, const __bf16* __restrict__ vT,
               __bf16* __restrict__ y, const int* __restrict__ winp) {
    __shared__ __align__(16) __bf16 Ks[2][64 * 64];    // 16 KB
    __shared__ __align__(16) __bf16 VTs[2][64 * 64];   // 16 KB
    __shared__ __align__(16) __bf16 Ps[4][16 * 64];    //  8 KB (XOR-swizzled)

    const int bx = blockIdx.x;                  // 0..31
    const int yq = blockIdx.y;                  // 0..31
    const int b = bx >> 4;
    const int qt = (yq < 16) ? yq : 47 - yq;    // 4-stripe complementary balance
    const int h = (bx + yq) & 15;               // mix heads across CUs
    const int q0 = qt * 64;
    const int tid = threadIdx.x, lane = tid & 63, w = tid >> 6;
    const int lhi = lane >> 4, llo = lane & 15;
    const int gsrc = (lane & 7) ^ ((lane >> 3) & 7);
    const int win = (h < 8) ? -1 : winp[0];
    const int winv = (win < 0) ? (1 << 30) : win;
    const int kvh = (h < 8) ? (h >> 1) : (4 + ((h - 8) >> 1));

    const __bf16* kbase = qkv + (size_t)(b * 2048) * 2048 + 1024 + kvh * 64;
    const __bf16* vtbase = vT + ((size_t)((b * 8 + kvh) * 64)) * 2048;

    int kts = 0;
    if (win >= 0) { int s = q0 - win; if (s > 0) kts = s >> 6; }

    // Q fragments in registers: lane q-row = q0 + w*16 + llo
    const __bf16* qrow = qkv + (size_t)(b * 2048 + q0 + w * 16 + llo) * 2048
                         + h * 64 + lhi * 8;
    bf16x8 qf[2];
    qf[0] = *(const bf16x8*)(qrow);
    qf[1] = *(const bf16x8*)(qrow + 32);

    auto STAGE = [&](int buf, int ktx) {
        #pragma unroll
        for (int rr = 0; rr < 2; ++rr) {
            int c = rr * 4 + w;
            int r = c * 8 + (lane >> 3);
            gload16(kbase + (size_t)(ktx * 64 + r) * 2048 + gsrc * 8,
                    (char*)&Ks[buf][0] + c * 1024);
            gload16(vtbase + (size_t)r * 2048 + ktx * 64 + gsrc * 8,
                    (char*)&VTs[buf][0] + c * 1024);
        }
    };

    f32x4 oaccT[4] = {};
    float mrow = -1e30f, lrow = 0.f;
    int cur = 0;
    STAGE(0, kts);

    const int pswz = (llo & 7) << 4;            // per-row XOR swizzle

    for (int kt = kts; kt <= qt; ++kt) {
        __syncthreads();                         // cur landed; prev reads done
        if (kt < qt) STAGE(cur ^ 1, kt + 1);     // flies under compute

        // ---- S^T = K · Q^T : D[key][q], q = llo ----
        f32x4 sacc[4] = {};
        #pragma unroll
        for (int ks = 0; ks < 2; ++ks) {
            #pragma unroll
            for (int kj = 0; kj < 4; ++kj) {
                int rb = kj * 16 + llo;
                bf16x8 bk = *(const bf16x8*)((const char*)&Ks[cur][0]
                    + rb * 128 + (((ks * 4 + lhi) ^ (rb & 7)) << 4));
                sacc[kj] = MFMA16(bk, qf[ks], sacc[kj]);
            }
        }

        const bool needMask = (kt == qt) || (win >= 0 && kt * 64 < q0 + 63 - winv);

        float sv[16];
        #pragma unroll
        for (int kj = 0; kj < 4; ++kj)
            #pragma unroll
            for (int r = 0; r < 4; ++r)
                sv[kj * 4 + r] = sacc[kj][r];
        if (needMask) {
            int qrowi = q0 + w * 16 + llo;
            #pragma unroll
            for (int kj = 0; kj < 4; ++kj)
                #pragma unroll
                for (int r = 0; r < 4; ++r) {
                    int key = kt * 64 + kj * 16 + lhi * 4 + r;
                    bool ok = (key <= qrowi) && (qrowi - key <= winv);
                    if (!ok) sv[kj * 4 + r] = -1e30f;
                }
        }
        // row max: 15 in-lane + 2 shfl (row spread over 4 lanes llo+16*lhi)
        float rm = sv[0];
        #pragma unroll
        for (int t = 1; t < 16; ++t) rm = fmaxf(rm, sv[t]);
        rm = fmaxf(rm, __shfl_xor(rm, 16, 64));
        rm = fmaxf(rm, __shfl_xor(rm, 32, 64));

        // defer-max: rescale only when max grew by >8 (log2 domain)
        if (__any(rm > mrow + 8.f)) {
            float mnew = fmaxf(mrow, rm);
            float alpha = __builtin_amdgcn_exp2f(mrow - mnew);
            mrow = mnew;
            lrow *= alpha;
            #pragma unroll
            for (int dj = 0; dj < 4; ++dj) oaccT[dj] *= alpha;
        }

        float p[16], rs = 0.f;
        #pragma unroll
        for (int t = 0; t < 16; ++t) {
            p[t] = __builtin_amdgcn_exp2f(sv[t] - mrow);
            rs += p[t];
        }
        rs += __shfl_xor(rs, 16, 64);
        rs += __shfl_xor(rs, 32, 64);
        lrow += rs;

        // P -> per-wave swizzled LDS (row=llo, byte=key*2 ^ pswz)
        #pragma unroll
        for (int kj = 0; kj < 4; ++kj) {
            bf16x4 pk = { (__bf16)p[kj * 4 + 0], (__bf16)p[kj * 4 + 1],
                          (__bf16)p[kj * 4 + 2], (__bf16)p[kj * 4 + 3] };
            *(bf16x4*)((char*)&Ps[w][0]
                + ((llo * 128 + kj * 32 + lhi * 8) ^ pswz)) = pk;
        }

        // ---- O^T += V^T · P^T : D[d][q], q = llo ----
        #pragma unroll
        for (int ks = 0; ks < 2; ++ks) {
            bf16x8 ap = *(const bf16x8*)((const char*)&Ps[w][0]
                + ((llo * 128 + ks * 64 + lhi * 16) ^ pswz));
            #pragma unroll
            for (int dj = 0; dj < 4; ++dj) {
                int rv = dj * 16 + llo;
                bf16x8 bv = *(const bf16x8*)((const char*)&VTs[cur][0]
                    + rv * 128 + (((ks * 4 + lhi) ^ (rv & 7)) << 4));
                oaccT[dj] = MFMA16(bv, ap, oaccT[dj]);
            }
        }
        cur ^= 1;
    }

    float inv = 1.0f / lrow;
    int row = b * 2048 + q0 + w * 16 + llo;
    #pragma unroll
    for (int dj = 0; dj < 4; ++dj) {
        bf16x4 o = { (__bf16)(oaccT[dj][0] * inv), (__bf16)(oaccT[dj][1] * inv),
                     (__bf16)(oaccT[dj][2] * inv), (__bf16)(oaccT[dj][3] * inv) };
        *(bf16x4*)(&y[(size_t)row * 1024 + h * 64 + dj * 16 + lhi * 4]) = o;
    }
}

// ---------------------------------------------------------------------------
extern "C" void kernel_launch(void* const* d_in, const int* in_sizes, int n_in,
                              void* d_out, int out_size, void* d_ws, size_t ws_size,
                              hipStream_t stream) {
    const float* x     = (const float*)d_in[0];
    const float* ve    = (const float*)d_in[1];
    const float* cosb  = (const float*)d_in[2];
    const float* sinb  = (const float*)d_in[3];
    const float* Wq    = (const float*)d_in[4];
    const float* Wk    = (const float*)d_in[5];
    const float* Wv    = (const float*)d_in[6];
    const float* Wproj = (const float*)d_in[7];
    const float* Wg    = (const float*)d_in[8];
    const int*   winp  = (const int*)d_in[9];

    char* ws = (char*)d_ws;
    __bf16* qkv    = (__bf16*)(ws);                       // 16 MB  [4096][2048]
    __bf16* vT     = (__bf16*)(ws + (16u << 20));         //  4 MB  [2*8*64][2048]
    __bf16* ybuf   = (__bf16*)(ws + (20u << 20));         //  8 MB  [4096][1024]
    __bf16* xb     = (__bf16*)(ws + (28u << 20));         //  8 MB  [4096][1024]
    __bf16* wqkvt  = (__bf16*)(ws + (36u << 20));         //  4 MB  [2048][1024]
    __bf16* wprojt = (__bf16*)(ws + (40u << 20));         //  2 MB  [1024][1024]
    float*  gate   = (float*) (ws + (42u << 20));         // 128 KB [4096][8]

    castx_kernel<<<4096, 256, 0, stream>>>(x, xb);
    tw64_kernel<<<dim3(16, 16), 256, 0, stream>>>(Wq, wqkvt, 1024, 1024, 0);
    tw64_kernel<<<dim3(8, 16), 256, 0, stream>>>(Wk, wqkvt, 512, 1024, 1024);
    tw64_kernel<<<dim3(8, 16), 256, 0, stream>>>(Wv, wqkvt, 512, 1024, 1536);
    tw64_kernel<<<dim3(16, 16), 256, 0, stream>>>(Wproj, wprojt, 1024, 1024, 0);
    gate_kernel<<<128, 256, 0, stream>>>(x, Wg, gate);

    gemm_bf16<__bf16><<<dim3(16, 32), 256, 0, stream>>>(xb, wqkvt, qkv, 4096, 2048, 1024);
    rrv_qk<<<dim3(24, 1024), 256, 0, stream>>>(qkv, cosb, sinb);
    vgate_t<<<dim3(64, 8), 256, 0, stream>>>(qkv, ve, gate, vT);
    attn_mfma<<<dim3(32, 32), 256, 0, stream>>>(qkv, vT, ybuf, winp);
    gemm_bf16<float><<<dim3(8, 32), 256, 0, stream>>>(ybuf, wprojt, (float*)d_out, 4096, 1024, 1024);
}

// Round 5
// 132.473 us; speedup vs baseline: 6.1854x; 1.0019x over previous
//
#include <hip/hip_runtime.h>
#include <hip/hip_bf16.h>
#include <math.h>

typedef __bf16 bf16x8 __attribute__((ext_vector_type(8)));
typedef __bf16 bf16x4 __attribute__((ext_vector_type(4)));
typedef float  f32x4  __attribute__((ext_vector_type(4)));

#define MFMA16(a, b, c) __builtin_amdgcn_mfma_f32_16x16x32_bf16((a), (b), (c), 0, 0, 0)

__device__ __forceinline__ void gload16(const void* g, void* lds) {
    __builtin_amdgcn_global_load_lds(
        (const __attribute__((address_space(1))) uint32_t*)g,
        (__attribute__((address_space(3))) uint32_t*)lds, 16, 0, 0);
}

// ---------------------------------------------------------------------------
// cast x (f32) -> bf16, 4 elements/thread
__global__ __launch_bounds__(256)
void castx_kernel(const float* __restrict__ x, __bf16* __restrict__ xb) {
    int i = blockIdx.x * 256 + threadIdx.x;
    float4 v = reinterpret_cast<const float4*>(x)[i];
    bf16x4 o = { (__bf16)v.x, (__bf16)v.y, (__bf16)v.z, (__bf16)v.w };
    *reinterpret_cast<bf16x4*>(xb + (size_t)i * 4) = o;
}

// ---------------------------------------------------------------------------
// transpose-cast weight tile: W [K][N] f32 -> dst [N][K] bf16 (row nt_off+n)
__global__ __launch_bounds__(256)
void tw64_kernel(const float* __restrict__ W, __bf16* __restrict__ dst,
                 int N, int K, int nt_off) {
    __shared__ __bf16 Ts[64 * 72];
    const int n0 = blockIdx.x * 64, k0 = blockIdx.y * 64;
    const int tid = threadIdx.x;
    {
        int r = tid >> 2;              // k-row 0..63
        int c0 = (tid & 3) * 16;       // n-col start
        const float4* s4 = reinterpret_cast<const float4*>(
            W + (size_t)(k0 + r) * N + n0 + c0);
        float val[16];
        #pragma unroll
        for (int q = 0; q < 4; ++q) {
            float4 v = s4[q];
            val[q * 4 + 0] = v.x; val[q * 4 + 1] = v.y;
            val[q * 4 + 2] = v.z; val[q * 4 + 3] = v.w;
        }
        #pragma unroll
        for (int j = 0; j < 16; ++j) Ts[(c0 + j) * 72 + r] = (__bf16)val[j];
    }
    __syncthreads();
    {
        int n = tid >> 2, kg = (tid & 3) * 16;
        __bf16* out = dst + (size_t)(nt_off + n0 + n) * K + k0 + kg;
        bf16x8 t0 = *reinterpret_cast<const bf16x8*>(&Ts[n * 72 + kg]);
        bf16x8 t1 = *reinterpret_cast<const bf16x8*>(&Ts[n * 72 + kg + 8]);
        *reinterpret_cast<bf16x8*>(out) = t0;
        *reinterpret_cast<bf16x8*>(out + 8) = t1;
    }
}

// ---------------------------------------------------------------------------
// gate = 2*sigmoid(x[:, :32] @ Wg)   (f32, tiny)
__global__ void gate_kernel(const float* __restrict__ x, const float* __restrict__ Wg,
                            float* __restrict__ gate) {
    int idx = blockIdx.x * blockDim.x + threadIdx.x;   // row*8 + j
    if (idx >= 4096 * 8) return;
    int row = idx >> 3, j = idx & 7;
    float z = 0.f;
    #pragma unroll
    for (int i = 0; i < 32; ++i)
        z = fmaf(x[(size_t)row * 1024 + i], Wg[i * 8 + j], z);
    gate[idx] = 2.0f / (1.0f + expf(-z));
}

// ---------------------------------------------------------------------------
// bf16 MFMA GEMM: C(MxN) = A(MxK) @ Bt(NxK)^T ; 128x128 tile, BK=64, 4 waves
template <typename OutT>
__global__ __launch_bounds__(256)
void gemm_bf16(const __bf16* __restrict__ A, const __bf16* __restrict__ Bt,
               OutT* __restrict__ C, int M, int N, int K) {
    __shared__ __align__(16) __bf16 As[128 * 64];
    __shared__ __align__(16) __bf16 Bs[128 * 64];
    const int tid = threadIdx.x;
    const int lane = tid & 63, w = tid >> 6;
    const int wr = w >> 1, wc = w & 1;
    const int bm = blockIdx.y * 128, bn = blockIdx.x * 128;
    const int lhi = lane >> 4, llo = lane & 15;
    const int gsrc = (lane & 7) ^ ((lane >> 3) & 7);   // pre-swizzled source group

    f32x4 acc[4][4] = {};

    for (int k0 = 0; k0 < K; k0 += 64) {
        __syncthreads();
        const __bf16* Ab = A + (size_t)bm * K + k0;
        const __bf16* Bb = Bt + (size_t)bn * K + k0;
        #pragma unroll
        for (int rr = 0; rr < 4; ++rr) {
            int c = rr * 4 + w;
            int r = c * 8 + (lane >> 3);
            gload16(Ab + (size_t)r * K + gsrc * 8, (char*)As + c * 1024);
            gload16(Bb + (size_t)r * K + gsrc * 8, (char*)Bs + c * 1024);
        }
        __syncthreads();

        #pragma unroll
        for (int ks = 0; ks < 2; ++ks) {
            bf16x8 af[4], bfr[4];
            int g = ks * 4 + lhi;
            #pragma unroll
            for (int i = 0; i < 4; ++i) {
                int ra = wr * 64 + i * 16 + llo;
                af[i] = *reinterpret_cast<const bf16x8*>(
                    (const char*)As + ra * 128 + ((g ^ (ra & 7)) << 4));
                int rb = wc * 64 + i * 16 + llo;
                bfr[i] = *reinterpret_cast<const bf16x8*>(
                    (const char*)Bs + rb * 128 + ((g ^ (rb & 7)) << 4));
            }
            #pragma unroll
            for (int i = 0; i < 4; ++i)
                #pragma unroll
                for (int j = 0; j < 4; ++j)
                    acc[i][j] = MFMA16(af[i], bfr[j], acc[i][j]);
        }
    }

    #pragma unroll
    for (int i = 0; i < 4; ++i) {
        #pragma unroll
        for (int j = 0; j < 4; ++j) {
            int col = bn + wc * 64 + j * 16 + llo;
            #pragma unroll
            for (int r = 0; r < 4; ++r) {
                int row = bm + wr * 64 + i * 16 + lhi * 4 + r;
                C[(size_t)row * N + col] = (OutT)acc[i][j][r];
            }
        }
    }
}

// ---------------------------------------------------------------------------
// RoPE + RMS-norm on q (u<16) and k (u in 16..24) heads, bf16 in/out.
// Q heads additionally scaled by 0.125*log2(e) (exp2-domain softmax).
__global__ __launch_bounds__(256)
void rrv_qk(__bf16* __restrict__ qkv, const float* __restrict__ cosb,
            const float* __restrict__ sinb) {
    const int u = blockIdx.x;                       // 0..23
    const int row = blockIdx.y * 4 + (threadIdx.x >> 6);
    const int d = threadIdx.x & 63;
    const int t = row & 2047;
    const int off = (u < 16) ? u * 64 : 1024 + (u - 16) * 64;
    __bf16* p = qkv + (size_t)row * 2048 + off;
    float v = (float)p[d];
    float partner = __shfl(v, d ^ 32, 64);
    float r;
    if (d < 32) {
        float cs = cosb[t * 32 + d], sn = sinb[t * 32 + d];
        r = v * cs + partner * sn;
    } else {
        float cs = cosb[t * 32 + d - 32], sn = sinb[t * 32 + d - 32];
        r = -partner * sn + v * cs;
    }
    float s = r * r;
    #pragma unroll
    for (int mm = 1; mm < 64; mm <<= 1) s += __shfl_xor(s, mm, 64);
    r *= rsqrtf(s * (1.0f / 64.0f) + 1.1920929e-07f);
    if (u < 16) r *= 0.18033688011116012f;          // 0.125 * log2(e)
    p[d] = (__bf16)r;
}

// ---------------------------------------------------------------------------
// v = v + gate*ve, then write TRANSPOSED into vT[(b*8+h)*64 + d][t] (bf16)
__global__ __launch_bounds__(256)
void vgate_t(const __bf16* __restrict__ qkv, const float* __restrict__ ve,
             const float* __restrict__ gate, __bf16* __restrict__ vT) {
    __shared__ __bf16 Ts[64 * 72];
    const int ch = blockIdx.x;      // 0..63 (row chunk of 64)
    const int h = blockIdx.y;       // 0..7
    const int tid = threadIdx.x;
    {
        int r = tid >> 2, c0 = (tid & 3) * 16;
        int grow = ch * 64 + r;
        float g = gate[grow * 8 + h];
        const __bf16* vp = qkv + (size_t)grow * 2048 + 1536 + h * 64 + c0;
        const float* vep = ve + (size_t)grow * 512 + h * 64 + c0;
        bf16x8 v0 = *reinterpret_cast<const bf16x8*>(vp);
        bf16x8 v1 = *reinterpret_cast<const bf16x8*>(vp + 8);
        #pragma unroll
        for (int j = 0; j < 8; ++j) {
            Ts[(c0 + j) * 72 + r]     = (__bf16)((float)v0[j] + g * vep[j]);
            Ts[(c0 + 8 + j) * 72 + r] = (__bf16)((float)v1[j] + g * vep[8 + j]);
        }
    }
    __syncthreads();
    {
        int d = tid >> 2, t0l = (tid & 3) * 16;
        int b = ch >> 5, tloc = (ch & 31) * 64;
        __bf16* out = vT + ((size_t)((b * 8 + h) * 64 + d)) * 2048 + tloc + t0l;
        bf16x8 t0 = *reinterpret_cast<const bf16x8*>(&Ts[d * 72 + t0l]);
        bf16x8 t1 = *reinterpret_cast<const bf16x8*>(&Ts[d * 72 + t0l + 8]);
        *reinterpret_cast<bf16x8*>(out) = t0;
        *reinterpret_cast<bf16x8*>(out + 8) = t1;
    }
}

// ---------------------------------------------------------------------------
// MFMA flash attention v4: QBLK=64 (4 waves x 16 q-rows), KVBLK=64.
// LPT dispatch (longest qt first), Q in registers, swapped-S^T MFMA,
// lane-local defer-max (shfls only on trigger), deferred lrow reduction,
// XOR-swizzled per-wave P, setprio around MFMA clusters.
__global__ __launch_bounds__(256, 4)
void attn_mfma(const __bf16* __restrict__ qkv, const __bf16* __restrict__ vT,
               __bf16* __restrict__ y, const int* __restrict__ winp) {
    __shared__ __align__(16) __bf16 Ks[2][64 * 64];    // 16 KB
    __shared__ __align__(16) __bf16 VTs[2][64 * 64];   // 16 KB
    __shared__ __align__(16) __bf16 Ps[4][16 * 64];    //  8 KB (XOR-swizzled)

    // LPT decode: qt descending with dispatch order (longest jobs first)
    const int bid = blockIdx.x;                 // 0..1023
    const int qt = 31 - (bid >> 5);
    const int sub = bid & 31;
    const int b = sub >> 4;
    const int h = ((sub & 15) + qt) & 15;       // rotate heads across waves
    const int q0 = qt * 64;
    const int tid = threadIdx.x, lane = tid & 63, w = tid >> 6;
    const int lhi = lane >> 4, llo = lane & 15;
    const int gsrc = (lane & 7) ^ ((lane >> 3) & 7);
    const int win = (h < 8) ? -1 : winp[0];
    const int winv = (win < 0) ? (1 << 30) : win;
    const int kvh = (h < 8) ? (h >> 1) : (4 + ((h - 8) >> 1));

    const __bf16* kbase = qkv + (size_t)(b * 2048) * 2048 + 1024 + kvh * 64;
    const __bf16* vtbase = vT + ((size_t)((b * 8 + kvh) * 64)) * 2048;

    int kts = 0;
    if (win >= 0) { int s = q0 - win; if (s > 0) kts = s >> 6; }

    // Q fragments in registers: lane q-row = q0 + w*16 + llo
    const __bf16* qrow = qkv + (size_t)(b * 2048 + q0 + w * 16 + llo) * 2048
                         + h * 64 + lhi * 8;
    bf16x8 qf[2];
    qf[0] = *(const bf16x8*)(qrow);
    qf[1] = *(const bf16x8*)(qrow + 32);

    auto STAGE = [&](int buf, int ktx) {
        #pragma unroll
        for (int rr = 0; rr < 2; ++rr) {
            int c = rr * 4 + w;
            int r = c * 8 + (lane >> 3);
            gload16(kbase + (size_t)(ktx * 64 + r) * 2048 + gsrc * 8,
                    (char*)&Ks[buf][0] + c * 1024);
            gload16(vtbase + (size_t)r * 2048 + ktx * 64 + gsrc * 8,
                    (char*)&VTs[buf][0] + c * 1024);
        }
    };

    f32x4 oaccT[4] = {};
    float mrow = -1e30f, lrow = 0.f;            // lrow = per-lane partial
    int cur = 0;
    STAGE(0, kts);

    const int pswz = (llo & 7) << 4;            // per-row XOR swizzle

    for (int kt = kts; kt <= qt; ++kt) {
        __syncthreads();                         // cur landed; prev reads done
        if (kt < qt) STAGE(cur ^ 1, kt + 1);     // flies under compute

        // ---- S^T = K · Q^T : D[key][q], q = llo ----
        f32x4 sacc[4] = {};
        __builtin_amdgcn_s_setprio(1);
        #pragma unroll
        for (int ks = 0; ks < 2; ++ks) {
            #pragma unroll
            for (int kj = 0; kj < 4; ++kj) {
                int rb = kj * 16 + llo;
                bf16x8 bk = *(const bf16x8*)((const char*)&Ks[cur][0]
                    + rb * 128 + (((ks * 4 + lhi) ^ (rb & 7)) << 4));
                sacc[kj] = MFMA16(bk, qf[ks], sacc[kj]);
            }
        }
        __builtin_amdgcn_s_setprio(0);

        const bool needMask = (kt == qt) || (win >= 0 && kt * 64 < q0 + 63 - winv);

        float sv[16];
        #pragma unroll
        for (int kj = 0; kj < 4; ++kj)
            #pragma unroll
            for (int r = 0; r < 4; ++r)
                sv[kj * 4 + r] = sacc[kj][r];
        if (needMask) {
            int qrowi = q0 + w * 16 + llo;
            #pragma unroll
            for (int kj = 0; kj < 4; ++kj)
                #pragma unroll
                for (int r = 0; r < 4; ++r) {
                    int key = kt * 64 + kj * 16 + lhi * 4 + r;
                    bool ok = (key <= qrowi) && (qrowi - key <= winv);
                    if (!ok) sv[kj * 4 + r] = -__builtin_inff();
                }
        }
        // lane-local max, tree reduction (depth 4)
        float mt[8];
        #pragma unroll
        for (int t = 0; t < 8; ++t) mt[t] = fmaxf(sv[t], sv[t + 8]);
        #pragma unroll
        for (int t = 0; t < 4; ++t) mt[t] = fmaxf(mt[t], mt[t + 4]);
        float rmloc = fmaxf(fmaxf(mt[0], mt[1]), fmaxf(mt[2], mt[3]));

        // defer-max: cross-lane shfls ONLY when some lane exceeds mrow+8
        if (__any(rmloc > mrow + 8.f)) {
            float rm = rmloc;
            rm = fmaxf(rm, __shfl_xor(rm, 16, 64));
            rm = fmaxf(rm, __shfl_xor(rm, 32, 64));
            float mnew = fmaxf(mrow, rm);
            float alpha = __builtin_amdgcn_exp2f(mrow - mnew);
            mrow = mnew;
            lrow *= alpha;
            #pragma unroll
            for (int dj = 0; dj < 4; ++dj) oaccT[dj] *= alpha;
        }

        float p[16], rs = 0.f;
        #pragma unroll
        for (int t = 0; t < 16; ++t) {
            p[t] = __builtin_amdgcn_exp2f(sv[t] - mrow);
            rs += p[t];
        }
        lrow += rs;                              // per-lane partial; reduce later

        // P -> per-wave swizzled LDS (row=llo, byte=key*2 ^ pswz)
        #pragma unroll
        for (int kj = 0; kj < 4; ++kj) {
            bf16x4 pk = { (__bf16)p[kj * 4 + 0], (__bf16)p[kj * 4 + 1],
                          (__bf16)p[kj * 4 + 2], (__bf16)p[kj * 4 + 3] };
            *(bf16x4*)((char*)&Ps[w][0]
                + ((llo * 128 + kj * 32 + lhi * 8) ^ pswz)) = pk;
        }

        // ---- O^T += V^T · P^T : D[d][q], q = llo ----
        __builtin_amdgcn_s_setprio(1);
        #pragma unroll
        for (int ks = 0; ks < 2; ++ks) {
            bf16x8 ap = *(const bf16x8*)((const char*)&Ps[w][0]
                + ((llo * 128 + ks * 64 + lhi * 16) ^ pswz));
            #pragma unroll
            for (int dj = 0; dj < 4; ++dj) {
                int rv = dj * 16 + llo;
                bf16x8 bv = *(const bf16x8*)((const char*)&VTs[cur][0]
                    + rv * 128 + (((ks * 4 + lhi) ^ (rv & 7)) << 4));
                oaccT[dj] = MFMA16(bv, ap, oaccT[dj]);
            }
        }
        __builtin_amdgcn_s_setprio(0);
        cur ^= 1;
    }

    // final cross-lane lrow reduction (once)
    lrow += __shfl_xor(lrow, 16, 64);
    lrow += __shfl_xor(lrow, 32, 64);

    float inv = 1.0f / lrow;
    int row = b * 2048 + q0 + w * 16 + llo;
    #pragma unroll
    for (int dj = 0; dj < 4; ++dj) {
        bf16x4 o = { (__bf16)(oaccT[dj][0] * inv), (__bf16)(oaccT[dj][1] * inv),
                     (__bf16)(oaccT[dj][2] * inv), (__bf16)(oaccT[dj][3] * inv) };
        *(bf16x4*)(&y[(size_t)row * 1024 + h * 64 + dj * 16 + lhi * 4]) = o;
    }
}

// ---------------------------------------------------------------------------
extern "C" void kernel_launch(void* const* d_in, const int* in_sizes, int n_in,
                              void* d_out, int out_size, void* d_ws, size_t ws_size,
                              hipStream_t stream) {
    const float* x     = (const float*)d_in[0];
    const float* ve    = (const float*)d_in[1];
    const float* cosb  = (const float*)d_in[2];
    const float* sinb  = (const float*)d_in[3];
    const float* Wq    = (const float*)d_in[4];
    const float* Wk    = (const float*)d_in[5];
    const float* Wv    = (const float*)d_in[6];
    const float* Wproj = (const float*)d_in[7];
    const float* Wg    = (const float*)d_in[8];
    const int*   winp  = (const int*)d_in[9];

    char* ws = (char*)d_ws;
    __bf16* qkv    = (__bf16*)(ws);                       // 16 MB  [4096][2048]
    __bf16* vT     = (__bf16*)(ws + (16u << 20));         //  4 MB  [2*8*64][2048]
    __bf16* ybuf   = (__bf16*)(ws + (20u << 20));         //  8 MB  [4096][1024]
    __bf16* xb     = (__bf16*)(ws + (28u << 20));         //  8 MB  [4096][1024]
    __bf16* wqkvt  = (__bf16*)(ws + (36u << 20));         //  4 MB  [2048][1024]
    __bf16* wprojt = (__bf16*)(ws + (40u << 20));         //  2 MB  [1024][1024]
    float*  gate   = (float*) (ws + (42u << 20));         // 128 KB [4096][8]

    castx_kernel<<<4096, 256, 0, stream>>>(x, xb);
    tw64_kernel<<<dim3(16, 16), 256, 0, stream>>>(Wq, wqkvt, 1024, 1024, 0);
    tw64_kernel<<<dim3(8, 16), 256, 0, stream>>>(Wk, wqkvt, 512, 1024, 1024);
    tw64_kernel<<<dim3(8, 16), 256, 0, stream>>>(Wv, wqkvt, 512, 1024, 1536);
    tw64_kernel<<<dim3(16, 16), 256, 0, stream>>>(Wproj, wprojt, 1024, 1024, 0);
    gate_kernel<<<128, 256, 0, stream>>>(x, Wg, gate);

    gemm_bf16<__bf16><<<dim3(16, 32), 256, 0, stream>>>(xb, wqkvt, qkv, 4096, 2048, 1024);
    rrv_qk<<<dim3(24, 1024), 256, 0, stream>>>(qkv, cosb, sinb);
    vgate_t<<<dim3(64, 8), 256, 0, stream>>>(qkv, ve, gate, vT);
    attn_mfma<<<dim3(1024), 256, 0, stream>>>(qkv, vT, ybuf, winp);
    gemm_bf16<float><<<dim3(8, 32), 256, 0, stream>>>(ybuf, wprojt, (float*)d_out, 4096, 1024, 1024);
}

// Round 6
// 129.239 us; speedup vs baseline: 6.3402x; 1.0250x over previous
//
#include <hip/hip_runtime.h>
#include <hip/hip_bf16.h>
#include <math.h>

typedef __bf16 bf16x8 __attribute__((ext_vector_type(8)));
typedef __bf16 bf16x4 __attribute__((ext_vector_type(4)));
typedef float  f32x4  __attribute__((ext_vector_type(4)));

#define MFMA16(a, b, c) __builtin_amdgcn_mfma_f32_16x16x32_bf16((a), (b), (c), 0, 0, 0)

__device__ __forceinline__ void gload16(const void* g, void* lds) {
    __builtin_amdgcn_global_load_lds(
        (const __attribute__((address_space(1))) uint32_t*)g,
        (__attribute__((address_space(3))) uint32_t*)lds, 16, 0, 0);
}

// ---------------------------------------------------------------------------
// prep: cast x -> bf16 (blocks 0..4095) + gate (blocks 4096..4223)
__global__ __launch_bounds__(256)
void prep_kernel(const float* __restrict__ x, __bf16* __restrict__ xb,
                 const float* __restrict__ Wg, float* __restrict__ gate) {
    const int bx = blockIdx.x;
    if (bx < 4096) {
        int i = bx * 256 + threadIdx.x;
        float4 v = reinterpret_cast<const float4*>(x)[i];
        bf16x4 o = { (__bf16)v.x, (__bf16)v.y, (__bf16)v.z, (__bf16)v.w };
        *reinterpret_cast<bf16x4*>(xb + (size_t)i * 4) = o;
    } else {
        int idx = (bx - 4096) * 256 + threadIdx.x;   // row*8 + j
        int row = idx >> 3, j = idx & 7;
        float z = 0.f;
        #pragma unroll
        for (int i = 0; i < 32; ++i)
            z = fmaf(x[(size_t)row * 1024 + i], Wg[i * 8 + j], z);
        gate[idx] = 2.0f / (1.0f + expf(-z));
    }
}

// ---------------------------------------------------------------------------
// transpose-cast all weights: z=0 Wq, z=1 Wk, z=2 Wv (into wqkvt), z=3 Wproj
__global__ __launch_bounds__(256)
void tw_all(const float* __restrict__ Wq, const float* __restrict__ Wk,
            const float* __restrict__ Wv, const float* __restrict__ Wproj,
            __bf16* __restrict__ wqkvt, __bf16* __restrict__ wprojt) {
    __shared__ __bf16 Ts[64 * 72];
    const int z = blockIdx.z;
    const float* W = (z == 0) ? Wq : (z == 1) ? Wk : (z == 2) ? Wv : Wproj;
    __bf16* dst = (z == 3) ? wprojt : wqkvt;
    const int N = (z == 1 || z == 2) ? 512 : 1024;
    const int nt_off = (z == 1) ? 1024 : (z == 2) ? 1536 : 0;
    const int n0 = blockIdx.x * 64, k0 = blockIdx.y * 64;
    if (n0 >= N) return;
    const int tid = threadIdx.x;
    {
        int r = tid >> 2;              // k-row 0..63
        int c0 = (tid & 3) * 16;       // n-col start
        const float4* s4 = reinterpret_cast<const float4*>(
            W + (size_t)(k0 + r) * N + n0 + c0);
        float val[16];
        #pragma unroll
        for (int q = 0; q < 4; ++q) {
            float4 v = s4[q];
            val[q * 4 + 0] = v.x; val[q * 4 + 1] = v.y;
            val[q * 4 + 2] = v.z; val[q * 4 + 3] = v.w;
        }
        #pragma unroll
        for (int j = 0; j < 16; ++j) Ts[(c0 + j) * 72 + r] = (__bf16)val[j];
    }
    __syncthreads();
    {
        int n = tid >> 2, kg = (tid & 3) * 16;
        __bf16* out = dst + (size_t)(nt_off + n0 + n) * 1024 + k0 + kg;
        bf16x8 t0 = *reinterpret_cast<const bf16x8*>(&Ts[n * 72 + kg]);
        bf16x8 t1 = *reinterpret_cast<const bf16x8*>(&Ts[n * 72 + kg + 8]);
        *reinterpret_cast<bf16x8*>(out) = t0;
        *reinterpret_cast<bf16x8*>(out + 8) = t1;
    }
}

// ---------------------------------------------------------------------------
// bf16 MFMA GEMM: C(MxN) = A(MxK) @ Bt(NxK)^T ; 128x128 tile, BK=64, 4 waves,
// XCD-aware block swizzle.
template <typename OutT>
__global__ __launch_bounds__(256)
void gemm_bf16(const __bf16* __restrict__ A, const __bf16* __restrict__ Bt,
               OutT* __restrict__ C, int M, int N, int K) {
    __shared__ __align__(16) __bf16 As[128 * 64];
    __shared__ __align__(16) __bf16 Bs[128 * 64];
    const int tid = threadIdx.x;
    const int lane = tid & 63, w = tid >> 6;
    const int wr = w >> 1, wc = w & 1;
    // XCD swizzle (nwg % 8 == 0 for all our grids)
    const int nwg = gridDim.x * gridDim.y;
    const int id = blockIdx.y * gridDim.x + blockIdx.x;
    const int nid = (id & 7) * (nwg >> 3) + (id >> 3);
    const int bxs = nid % gridDim.x, bys = nid / gridDim.x;
    const int bm = bys * 128, bn = bxs * 128;
    const int lhi = lane >> 4, llo = lane & 15;
    const int gsrc = (lane & 7) ^ ((lane >> 3) & 7);   // pre-swizzled source group

    f32x4 acc[4][4] = {};

    for (int k0 = 0; k0 < K; k0 += 64) {
        __syncthreads();
        const __bf16* Ab = A + (size_t)bm * K + k0;
        const __bf16* Bb = Bt + (size_t)bn * K + k0;
        #pragma unroll
        for (int rr = 0; rr < 4; ++rr) {
            int c = rr * 4 + w;
            int r = c * 8 + (lane >> 3);
            gload16(Ab + (size_t)r * K + gsrc * 8, (char*)As + c * 1024);
            gload16(Bb + (size_t)r * K + gsrc * 8, (char*)Bs + c * 1024);
        }
        __syncthreads();

        #pragma unroll
        for (int ks = 0; ks < 2; ++ks) {
            bf16x8 af[4], bfr[4];
            int g = ks * 4 + lhi;
            #pragma unroll
            for (int i = 0; i < 4; ++i) {
                int ra = wr * 64 + i * 16 + llo;
                af[i] = *reinterpret_cast<const bf16x8*>(
                    (const char*)As + ra * 128 + ((g ^ (ra & 7)) << 4));
                int rb = wc * 64 + i * 16 + llo;
                bfr[i] = *reinterpret_cast<const bf16x8*>(
                    (const char*)Bs + rb * 128 + ((g ^ (rb & 7)) << 4));
            }
            #pragma unroll
            for (int i = 0; i < 4; ++i)
                #pragma unroll
                for (int j = 0; j < 4; ++j)
                    acc[i][j] = MFMA16(af[i], bfr[j], acc[i][j]);
        }
    }

    #pragma unroll
    for (int i = 0; i < 4; ++i) {
        #pragma unroll
        for (int j = 0; j < 4; ++j) {
            int col = bn + wc * 64 + j * 16 + llo;
            #pragma unroll
            for (int r = 0; r < 4; ++r) {
                int row = bm + wr * 64 + i * 16 + lhi * 4 + r;
                C[(size_t)row * N + col] = (OutT)acc[i][j][r];
            }
        }
    }
}

// ---------------------------------------------------------------------------
// post: RoPE+RMS on q/k heads (ids < 24576) ; v-gate + transpose (rest).
// Q heads scaled by 0.125*log2(e) (exp2-domain softmax).
__global__ __launch_bounds__(256)
void post_kernel(__bf16* __restrict__ qkv, const float* __restrict__ ve,
                 const float* __restrict__ gate, const float* __restrict__ cosb,
                 const float* __restrict__ sinb, __bf16* __restrict__ vT) {
    const int id = blockIdx.x;
    const int tid = threadIdx.x;
    if (id < 24576) {
        const int u = id >> 10;                     // 0..23
        const int row = (id & 1023) * 4 + (tid >> 6);
        const int d = tid & 63;
        const int t = row & 2047;
        const int off = (u < 16) ? u * 64 : 1024 + (u - 16) * 64;
        __bf16* p = qkv + (size_t)row * 2048 + off;
        float v = (float)p[d];
        float partner = __shfl(v, d ^ 32, 64);
        float r;
        if (d < 32) {
            float cs = cosb[t * 32 + d], sn = sinb[t * 32 + d];
            r = v * cs + partner * sn;
        } else {
            float cs = cosb[t * 32 + d - 32], sn = sinb[t * 32 + d - 32];
            r = -partner * sn + v * cs;
        }
        float s = r * r;
        #pragma unroll
        for (int mm = 1; mm < 64; mm <<= 1) s += __shfl_xor(s, mm, 64);
        r *= rsqrtf(s * (1.0f / 64.0f) + 1.1920929e-07f);
        if (u < 16) r *= 0.18033688011116012f;      // 0.125 * log2(e)
        p[d] = (__bf16)r;
    } else {
        __shared__ __bf16 Ts[64 * 72];
        const int rem = id - 24576;
        const int ch = rem & 63;    // 64-row chunk
        const int h = rem >> 6;     // 0..7
        {
            int r = tid >> 2, c0 = (tid & 3) * 16;
            int grow = ch * 64 + r;
            float g = gate[grow * 8 + h];
            const __bf16* vp = qkv + (size_t)grow * 2048 + 1536 + h * 64 + c0;
            const float* vep = ve + (size_t)grow * 512 + h * 64 + c0;
            bf16x8 v0 = *reinterpret_cast<const bf16x8*>(vp);
            bf16x8 v1 = *reinterpret_cast<const bf16x8*>(vp + 8);
            #pragma unroll
            for (int j = 0; j < 8; ++j) {
                Ts[(c0 + j) * 72 + r]     = (__bf16)((float)v0[j] + g * vep[j]);
                Ts[(c0 + 8 + j) * 72 + r] = (__bf16)((float)v1[j] + g * vep[8 + j]);
            }
        }
        __syncthreads();
        {
            int d = tid >> 2, t0l = (tid & 3) * 16;
            int b = ch >> 5, tloc = (ch & 31) * 64;
            __bf16* out = vT + ((size_t)((b * 8 + h) * 64 + d)) * 2048 + tloc + t0l;
            bf16x8 t0 = *reinterpret_cast<const bf16x8*>(&Ts[d * 72 + t0l]);
            bf16x8 t1 = *reinterpret_cast<const bf16x8*>(&Ts[d * 72 + t0l + 8]);
            *reinterpret_cast<bf16x8*>(out) = t0;
            *reinterpret_cast<bf16x8*>(out + 8) = t1;
        }
    }
}

// ---------------------------------------------------------------------------
// MFMA flash attention v5: QBLK=128 (8 waves x 16 q-rows), KVBLK=64, 512 thr.
// LDS 48KB -> 2-3 blocks/CU actually resident; all 512 blocks co-resident.
// Q in registers, swapped-S^T MFMA, lane-local defer-max, deferred lrow
// reduction, XOR-swizzled per-wave P, setprio around MFMA clusters.
__global__ __launch_bounds__(512, 6)
void attn_mfma(const __bf16* __restrict__ qkv, const __bf16* __restrict__ vT,
               __bf16* __restrict__ y, const int* __restrict__ winp) {
    __shared__ __align__(16) __bf16 Ks[2][64 * 64];    // 16 KB
    __shared__ __align__(16) __bf16 VTs[2][64 * 64];   // 16 KB
    __shared__ __align__(16) __bf16 Ps[8][16 * 64];    // 16 KB (XOR-swizzled)

    // LPT decode: qt descending (longest blocks first)
    const int bid = blockIdx.x;                 // 0..511
    const int qt = 15 - (bid >> 5);
    const int sub = bid & 31;
    const int b = sub >> 4;
    const int h = ((sub & 15) + qt) & 15;       // rotate heads across CUs
    const int q0 = qt * 128;
    const int tid = threadIdx.x, lane = tid & 63, w = tid >> 6;   // w 0..7
    const int lhi = lane >> 4, llo = lane & 15;
    const int gsrc = (lane & 7) ^ ((lane >> 3) & 7);
    const int win = (h < 8) ? -1 : winp[0];
    const int winv = (win < 0) ? (1 << 30) : win;
    const int kvh = (h < 8) ? (h >> 1) : (4 + ((h - 8) >> 1));

    const __bf16* kbase = qkv + (size_t)(b * 2048) * 2048 + 1024 + kvh * 64;
    const __bf16* vtbase = vT + ((size_t)((b * 8 + kvh) * 64)) * 2048;

    int kts = 0;
    if (win >= 0) { int s = q0 - win; if (s > 0) kts = s >> 6; }
    const int ktend = 2 * qt + 1;

    // Q fragments in registers: lane q-row = q0 + w*16 + llo
    const __bf16* qrow = qkv + (size_t)(b * 2048 + q0 + w * 16 + llo) * 2048
                         + h * 64 + lhi * 8;
    bf16x8 qf[2];
    qf[0] = *(const bf16x8*)(qrow);
    qf[1] = *(const bf16x8*)(qrow + 32);

    // each thread stages exactly 16B of K and 16B of V per tile
    auto STAGE = [&](int buf, int ktx) {
        int r = w * 8 + (lane >> 3);
        gload16(kbase + (size_t)(ktx * 64 + r) * 2048 + gsrc * 8,
                (char*)&Ks[buf][0] + w * 1024);
        gload16(vtbase + (size_t)r * 2048 + ktx * 64 + gsrc * 8,
                (char*)&VTs[buf][0] + w * 1024);
    };

    f32x4 oaccT[4] = {};
    float mrow = -1e30f, lrow = 0.f;            // lrow = per-lane partial
    int cur = 0;
    STAGE(0, kts);

    const int pswz = (llo & 7) << 4;            // per-row XOR swizzle

    for (int kt = kts; kt <= ktend; ++kt) {
        __syncthreads();                         // cur landed; prev reads done
        if (kt < ktend) STAGE(cur ^ 1, kt + 1);  // flies under compute

        // ---- S^T = K · Q^T : D[key][q], q = llo ----
        f32x4 sacc[4] = {};
        __builtin_amdgcn_s_setprio(1);
        #pragma unroll
        for (int ks = 0; ks < 2; ++ks) {
            #pragma unroll
            for (int kj = 0; kj < 4; ++kj) {
                int rb = kj * 16 + llo;
                bf16x8 bk = *(const bf16x8*)((const char*)&Ks[cur][0]
                    + rb * 128 + (((ks * 4 + lhi) ^ (rb & 7)) << 4));
                sacc[kj] = MFMA16(bk, qf[ks], sacc[kj]);
            }
        }
        __builtin_amdgcn_s_setprio(0);

        const bool needMask = (kt >= 2 * qt) ||
                              (win >= 0 && kt * 64 < q0 + 127 - winv);

        float sv[16];
        #pragma unroll
        for (int kj = 0; kj < 4; ++kj)
            #pragma unroll
            for (int r = 0; r < 4; ++r)
                sv[kj * 4 + r] = sacc[kj][r];
        if (needMask) {
            int qrowi = q0 + w * 16 + llo;
            #pragma unroll
            for (int kj = 0; kj < 4; ++kj)
                #pragma unroll
                for (int r = 0; r < 4; ++r) {
                    int key = kt * 64 + kj * 16 + lhi * 4 + r;
                    bool ok = (key <= qrowi) && (qrowi - key <= winv);
                    if (!ok) sv[kj * 4 + r] = -__builtin_inff();
                }
        }
        // lane-local max, tree reduction (depth 4)
        float mt[8];
        #pragma unroll
        for (int t = 0; t < 8; ++t) mt[t] = fmaxf(sv[t], sv[t + 8]);
        #pragma unroll
        for (int t = 0; t < 4; ++t) mt[t] = fmaxf(mt[t], mt[t + 4]);
        float rmloc = fmaxf(fmaxf(mt[0], mt[1]), fmaxf(mt[2], mt[3]));

        // defer-max: cross-lane shfls ONLY when some lane exceeds mrow+8
        if (__any(rmloc > mrow + 8.f)) {
            float rm = rmloc;
            rm = fmaxf(rm, __shfl_xor(rm, 16, 64));
            rm = fmaxf(rm, __shfl_xor(rm, 32, 64));
            float mnew = fmaxf(mrow, rm);
            float alpha = __builtin_amdgcn_exp2f(mrow - mnew);
            mrow = mnew;
            lrow *= alpha;
            #pragma unroll
            for (int dj = 0; dj < 4; ++dj) oaccT[dj] *= alpha;
        }

        float p[16], rs = 0.f;
        #pragma unroll
        for (int t = 0; t < 16; ++t) {
            p[t] = __builtin_amdgcn_exp2f(sv[t] - mrow);
            rs += p[t];
        }
        lrow += rs;                              // per-lane partial; reduce later

        // P -> per-wave swizzled LDS (row=llo, byte=key*2 ^ pswz)
        #pragma unroll
        for (int kj = 0; kj < 4; ++kj) {
            bf16x4 pk = { (__bf16)p[kj * 4 + 0], (__bf16)p[kj * 4 + 1],
                          (__bf16)p[kj * 4 + 2], (__bf16)p[kj * 4 + 3] };
            *(bf16x4*)((char*)&Ps[w][0]
                + ((llo * 128 + kj * 32 + lhi * 8) ^ pswz)) = pk;
        }

        // ---- O^T += V^T · P^T : D[d][q], q = llo ----
        __builtin_amdgcn_s_setprio(1);
        #pragma unroll
        for (int ks = 0; ks < 2; ++ks) {
            bf16x8 ap = *(const bf16x8*)((const char*)&Ps[w][0]
                + ((llo * 128 + ks * 64 + lhi * 16) ^ pswz));
            #pragma unroll
            for (int dj = 0; dj < 4; ++dj) {
                int rv = dj * 16 + llo;
                bf16x8 bv = *(const bf16x8*)((const char*)&VTs[cur][0]
                    + rv * 128 + (((ks * 4 + lhi) ^ (rv & 7)) << 4));
                oaccT[dj] = MFMA16(bv, ap, oaccT[dj]);
            }
        }
        __builtin_amdgcn_s_setprio(0);
        cur ^= 1;
    }

    // final cross-lane lrow reduction (once)
    lrow += __shfl_xor(lrow, 16, 64);
    lrow += __shfl_xor(lrow, 32, 64);

    float inv = 1.0f / lrow;
    int row = b * 2048 + q0 + w * 16 + llo;
    #pragma unroll
    for (int dj = 0; dj < 4; ++dj) {
        bf16x4 o = { (__bf16)(oaccT[dj][0] * inv), (__bf16)(oaccT[dj][1] * inv),
                     (__bf16)(oaccT[dj][2] * inv), (__bf16)(oaccT[dj][3] * inv) };
        *(bf16x4*)(&y[(size_t)row * 1024 + h * 64 + dj * 16 + lhi * 4]) = o;
    }
}

// ---------------------------------------------------------------------------
extern "C" void kernel_launch(void* const* d_in, const int* in_sizes, int n_in,
                              void* d_out, int out_size, void* d_ws, size_t ws_size,
                              hipStream_t stream) {
    const float* x     = (const float*)d_in[0];
    const float* ve    = (const float*)d_in[1];
    const float* cosb  = (const float*)d_in[2];
    const float* sinb  = (const float*)d_in[3];
    const float* Wq    = (const float*)d_in[4];
    const float* Wk    = (const float*)d_in[5];
    const float* Wv    = (const float*)d_in[6];
    const float* Wproj = (const float*)d_in[7];
    const float* Wg    = (const float*)d_in[8];
    const int*   winp  = (const int*)d_in[9];

    char* ws = (char*)d_ws;
    __bf16* qkv    = (__bf16*)(ws);                       // 16 MB  [4096][2048]
    __bf16* vT     = (__bf16*)(ws + (16u << 20));         //  4 MB  [2*8*64][2048]
    __bf16* ybuf   = (__bf16*)(ws + (20u << 20));         //  8 MB  [4096][1024]
    __bf16* xb     = (__bf16*)(ws + (28u << 20));         //  8 MB  [4096][1024]
    __bf16* wqkvt  = (__bf16*)(ws + (36u << 20));         //  4 MB  [2048][1024]
    __bf16* wprojt = (__bf16*)(ws + (40u << 20));         //  2 MB  [1024][1024]
    float*  gate   = (float*) (ws + (42u << 20));         // 128 KB [4096][8]

    prep_kernel<<<4224, 256, 0, stream>>>(x, xb, Wg, gate);
    tw_all<<<dim3(16, 16, 4), 256, 0, stream>>>(Wq, Wk, Wv, Wproj, wqkvt, wprojt);
    gemm_bf16<__bf16><<<dim3(16, 32), 256, 0, stream>>>(xb, wqkvt, qkv, 4096, 2048, 1024);
    post_kernel<<<25088, 256, 0, stream>>>(qkv, ve, gate, cosb, sinb, vT);
    attn_mfma<<<512, 512, 0, stream>>>(qkv, vT, ybuf, winp);
    gemm_bf16<float><<<dim3(8, 32), 256, 0, stream>>>(ybuf, wprojt, (float*)d_out, 4096, 1024, 1024);
}

// Round 7
// 119.548 us; speedup vs baseline: 6.8542x; 1.0811x over previous
//
#include <hip/hip_runtime.h>
#include <hip/hip_bf16.h>
#include <math.h>

typedef __bf16 bf16x8 __attribute__((ext_vector_type(8)));
typedef __bf16 bf16x4 __attribute__((ext_vector_type(4)));
typedef float  f32x4  __attribute__((ext_vector_type(4)));

#define MFMA16(a, b, c) __builtin_amdgcn_mfma_f32_16x16x32_bf16((a), (b), (c), 0, 0, 0)

__device__ __forceinline__ void gload16(const void* g, void* lds) {
    __builtin_amdgcn_global_load_lds(
        (const __attribute__((address_space(1))) uint32_t*)g,
        (__attribute__((address_space(3))) uint32_t*)lds, 16, 0, 0);
}

// ---------------------------------------------------------------------------
// prep: cast x -> bf16 (blocks 0..4095) + gate (blocks 4096..4223)
__global__ __launch_bounds__(256)
void prep_kernel(const float* __restrict__ x, __bf16* __restrict__ xb,
                 const float* __restrict__ Wg, float* __restrict__ gate) {
    const int bx = blockIdx.x;
    if (bx < 4096) {
        int i = bx * 256 + threadIdx.x;
        float4 v = reinterpret_cast<const float4*>(x)[i];
        bf16x4 o = { (__bf16)v.x, (__bf16)v.y, (__bf16)v.z, (__bf16)v.w };
        *reinterpret_cast<bf16x4*>(xb + (size_t)i * 4) = o;
    } else {
        int idx = (bx - 4096) * 256 + threadIdx.x;   // row*8 + j
        int row = idx >> 3, j = idx & 7;
        float z = 0.f;
        #pragma unroll
        for (int i = 0; i < 32; ++i)
            z = fmaf(x[(size_t)row * 1024 + i], Wg[i * 8 + j], z);
        gate[idx] = 2.0f / (1.0f + expf(-z));
    }
}

// ---------------------------------------------------------------------------
// transpose-cast all weights: z=0 Wq, z=1 Wk, z=2 Wv (into wqkvt), z=3 Wproj
__global__ __launch_bounds__(256)
void tw_all(const float* __restrict__ Wq, const float* __restrict__ Wk,
            const float* __restrict__ Wv, const float* __restrict__ Wproj,
            __bf16* __restrict__ wqkvt, __bf16* __restrict__ wprojt) {
    __shared__ __bf16 Ts[64 * 72];
    const int z = blockIdx.z;
    const float* W = (z == 0) ? Wq : (z == 1) ? Wk : (z == 2) ? Wv : Wproj;
    __bf16* dst = (z == 3) ? wprojt : wqkvt;
    const int N = (z == 1 || z == 2) ? 512 : 1024;
    const int nt_off = (z == 1) ? 1024 : (z == 2) ? 1536 : 0;
    const int n0 = blockIdx.x * 64, k0 = blockIdx.y * 64;
    if (n0 >= N) return;
    const int tid = threadIdx.x;
    {
        int r = tid >> 2;              // k-row 0..63
        int c0 = (tid & 3) * 16;       // n-col start
        const float4* s4 = reinterpret_cast<const float4*>(
            W + (size_t)(k0 + r) * N + n0 + c0);
        float val[16];
        #pragma unroll
        for (int q = 0; q < 4; ++q) {
            float4 v = s4[q];
            val[q * 4 + 0] = v.x; val[q * 4 + 1] = v.y;
            val[q * 4 + 2] = v.z; val[q * 4 + 3] = v.w;
        }
        #pragma unroll
        for (int j = 0; j < 16; ++j) Ts[(c0 + j) * 72 + r] = (__bf16)val[j];
    }
    __syncthreads();
    {
        int n = tid >> 2, kg = (tid & 3) * 16;
        __bf16* out = dst + (size_t)(nt_off + n0 + n) * 1024 + k0 + kg;
        bf16x8 t0 = *reinterpret_cast<const bf16x8*>(&Ts[n * 72 + kg]);
        bf16x8 t1 = *reinterpret_cast<const bf16x8*>(&Ts[n * 72 + kg + 8]);
        *reinterpret_cast<bf16x8*>(out) = t0;
        *reinterpret_cast<bf16x8*>(out + 8) = t1;
    }
}

// ---------------------------------------------------------------------------
// bf16 MFMA GEMM: C(MxN) = A(MxK) @ Bt(NxK)^T ; 128x128 tile, BK=64, 4 waves,
// XCD-aware block swizzle.
template <typename OutT>
__global__ __launch_bounds__(256)
void gemm_bf16(const __bf16* __restrict__ A, const __bf16* __restrict__ Bt,
               OutT* __restrict__ C, int M, int N, int K) {
    __shared__ __align__(16) __bf16 As[128 * 64];
    __shared__ __align__(16) __bf16 Bs[128 * 64];
    const int tid = threadIdx.x;
    const int lane = tid & 63, w = tid >> 6;
    const int wr = w >> 1, wc = w & 1;
    // XCD swizzle (nwg % 8 == 0 for all our grids)
    const int nwg = gridDim.x * gridDim.y;
    const int id = blockIdx.y * gridDim.x + blockIdx.x;
    const int nid = (id & 7) * (nwg >> 3) + (id >> 3);
    const int bxs = nid % gridDim.x, bys = nid / gridDim.x;
    const int bm = bys * 128, bn = bxs * 128;
    const int lhi = lane >> 4, llo = lane & 15;
    const int gsrc = (lane & 7) ^ ((lane >> 3) & 7);   // pre-swizzled source group

    f32x4 acc[4][4] = {};

    for (int k0 = 0; k0 < K; k0 += 64) {
        __syncthreads();
        const __bf16* Ab = A + (size_t)bm * K + k0;
        const __bf16* Bb = Bt + (size_t)bn * K + k0;
        #pragma unroll
        for (int rr = 0; rr < 4; ++rr) {
            int c = rr * 4 + w;
            int r = c * 8 + (lane >> 3);
            gload16(Ab + (size_t)r * K + gsrc * 8, (char*)As + c * 1024);
            gload16(Bb + (size_t)r * K + gsrc * 8, (char*)Bs + c * 1024);
        }
        __syncthreads();

        #pragma unroll
        for (int ks = 0; ks < 2; ++ks) {
            bf16x8 af[4], bfr[4];
            int g = ks * 4 + lhi;
            #pragma unroll
            for (int i = 0; i < 4; ++i) {
                int ra = wr * 64 + i * 16 + llo;
                af[i] = *reinterpret_cast<const bf16x8*>(
                    (const char*)As + ra * 128 + ((g ^ (ra & 7)) << 4));
                int rb = wc * 64 + i * 16 + llo;
                bfr[i] = *reinterpret_cast<const bf16x8*>(
                    (const char*)Bs + rb * 128 + ((g ^ (rb & 7)) << 4));
            }
            #pragma unroll
            for (int i = 0; i < 4; ++i)
                #pragma unroll
                for (int j = 0; j < 4; ++j)
                    acc[i][j] = MFMA16(af[i], bfr[j], acc[i][j]);
        }
    }

    #pragma unroll
    for (int i = 0; i < 4; ++i) {
        #pragma unroll
        for (int j = 0; j < 4; ++j) {
            int col = bn + wc * 64 + j * 16 + llo;
            #pragma unroll
            for (int r = 0; r < 4; ++r) {
                int row = bm + wr * 64 + i * 16 + lhi * 4 + r;
                C[(size_t)row * N + col] = (OutT)acc[i][j][r];
            }
        }
    }
}

// ---------------------------------------------------------------------------
// post: RoPE+RMS on q/k heads (ids < 24576) ; v-gate + transpose (rest).
// Q heads scaled by 0.125*log2(e) (exp2-domain softmax).
__global__ __launch_bounds__(256)
void post_kernel(__bf16* __restrict__ qkv, const float* __restrict__ ve,
                 const float* __restrict__ gate, const float* __restrict__ cosb,
                 const float* __restrict__ sinb, __bf16* __restrict__ vT) {
    const int id = blockIdx.x;
    const int tid = threadIdx.x;
    if (id < 24576) {
        const int u = id >> 10;                     // 0..23
        const int row = (id & 1023) * 4 + (tid >> 6);
        const int d = tid & 63;
        const int t = row & 2047;
        const int off = (u < 16) ? u * 64 : 1024 + (u - 16) * 64;
        __bf16* p = qkv + (size_t)row * 2048 + off;
        float v = (float)p[d];
        float partner = __shfl(v, d ^ 32, 64);
        float r;
        if (d < 32) {
            float cs = cosb[t * 32 + d], sn = sinb[t * 32 + d];
            r = v * cs + partner * sn;
        } else {
            float cs = cosb[t * 32 + d - 32], sn = sinb[t * 32 + d - 32];
            r = -partner * sn + v * cs;
        }
        float s = r * r;
        #pragma unroll
        for (int mm = 1; mm < 64; mm <<= 1) s += __shfl_xor(s, mm, 64);
        r *= rsqrtf(s * (1.0f / 64.0f) + 1.1920929e-07f);
        if (u < 16) r *= 0.18033688011116012f;      // 0.125 * log2(e)
        p[d] = (__bf16)r;
    } else {
        __shared__ __bf16 Ts[64 * 72];
        const int rem = id - 24576;
        const int ch = rem & 63;    // 64-row chunk
        const int h = rem >> 6;     // 0..7
        {
            int r = tid >> 2, c0 = (tid & 3) * 16;
            int grow = ch * 64 + r;
            float g = gate[grow * 8 + h];
            const __bf16* vp = qkv + (size_t)grow * 2048 + 1536 + h * 64 + c0;
            const float* vep = ve + (size_t)grow * 512 + h * 64 + c0;
            bf16x8 v0 = *reinterpret_cast<const bf16x8*>(vp);
            bf16x8 v1 = *reinterpret_cast<const bf16x8*>(vp + 8);
            #pragma unroll
            for (int j = 0; j < 8; ++j) {
                Ts[(c0 + j) * 72 + r]     = (__bf16)((float)v0[j] + g * vep[j]);
                Ts[(c0 + 8 + j) * 72 + r] = (__bf16)((float)v1[j] + g * vep[8 + j]);
            }
        }
        __syncthreads();
        {
            int d = tid >> 2, t0l = (tid & 3) * 16;
            int b = ch >> 5, tloc = (ch & 31) * 64;
            __bf16* out = vT + ((size_t)((b * 8 + h) * 64 + d)) * 2048 + tloc + t0l;
            bf16x8 t0 = *reinterpret_cast<const bf16x8*>(&Ts[d * 72 + t0l]);
            bf16x8 t1 = *reinterpret_cast<const bf16x8*>(&Ts[d * 72 + t0l + 8]);
            *reinterpret_cast<bf16x8*>(out) = t0;
            *reinterpret_cast<bf16x8*>(out + 8) = t1;
        }
    }
}

// ---------------------------------------------------------------------------
// MFMA flash attention v6: QBLK=64 (4 waves x 16 q-rows), KVBLK=64, grid 1024.
// XCD-locality: kvh in low 3 bits of blockIdx -> all blocks sharing one KV
// stream land on one XCD (KV stays L2-resident, HBM fetched once).
// LPT (qt descending) in upper bits. Fixed-max softmax (scores bounded by
// RMS-norm: |S*0.125*log2e| <= ~11.8, use M=12) -> no online max tracking.
__global__ __launch_bounds__(256, 4)
void attn_mfma(const __bf16* __restrict__ qkv, const __bf16* __restrict__ vT,
               __bf16* __restrict__ y, const int* __restrict__ winp) {
    __shared__ __align__(16) __bf16 Ks[2][64 * 64];    // 16 KB
    __shared__ __align__(16) __bf16 VTs[2][64 * 64];   // 16 KB
    __shared__ __align__(16) __bf16 Ps[4][16 * 64];    //  8 KB (XOR-swizzled)

    // decode: bid = (((31-qt)*2 + qh)*2 + b)*8 + kvh
    const int bid = blockIdx.x;                 // 0..1023
    const int kvh = bid & 7;
    int tdec = bid >> 3;
    const int b = tdec & 1; tdec >>= 1;
    const int qh = tdec & 1;
    const int qt = 31 - (tdec >> 1);
    const int h = (kvh < 4) ? (kvh * 2 + qh) : (8 + (kvh - 4) * 2 + qh);
    const int q0 = qt * 64;
    const int tid = threadIdx.x, lane = tid & 63, w = tid >> 6;
    const int lhi = lane >> 4, llo = lane & 15;
    const int gsrc = (lane & 7) ^ ((lane >> 3) & 7);
    const int win = (h < 8) ? -1 : winp[0];
    const int winv = (win < 0) ? (1 << 30) : win;

    const __bf16* kbase = qkv + (size_t)(b * 2048) * 2048 + 1024 + kvh * 64;
    const __bf16* vtbase = vT + ((size_t)((b * 8 + kvh) * 64)) * 2048;

    int kts = 0;
    if (win >= 0) { int s = q0 - win; if (s > 0) kts = s >> 6; }

    // Q fragments in registers: lane q-row = q0 + w*16 + llo
    const __bf16* qrow = qkv + (size_t)(b * 2048 + q0 + w * 16 + llo) * 2048
                         + h * 64 + lhi * 8;
    bf16x8 qf[2];
    qf[0] = *(const bf16x8*)(qrow);
    qf[1] = *(const bf16x8*)(qrow + 32);

    auto STAGE = [&](int buf, int ktx) {
        #pragma unroll
        for (int rr = 0; rr < 2; ++rr) {
            int c = rr * 4 + w;
            int r = c * 8 + (lane >> 3);
            gload16(kbase + (size_t)(ktx * 64 + r) * 2048 + gsrc * 8,
                    (char*)&Ks[buf][0] + c * 1024);
            gload16(vtbase + (size_t)r * 2048 + ktx * 64 + gsrc * 8,
                    (char*)&VTs[buf][0] + c * 1024);
        }
    };

    f32x4 oaccT[4] = {};
    float lrow = 0.f;                           // per-lane partial sum
    int cur = 0;
    STAGE(0, kts);

    const int pswz = (llo & 7) << 4;            // per-row XOR swizzle

    for (int kt = kts; kt <= qt; ++kt) {
        __syncthreads();                         // cur landed; prev reads done
        if (kt < qt) STAGE(cur ^ 1, kt + 1);     // flies under compute

        // ---- S^T = K · Q^T : D[key][q], q = llo ----
        f32x4 sacc[4] = {};
        __builtin_amdgcn_s_setprio(1);
        #pragma unroll
        for (int ks = 0; ks < 2; ++ks) {
            #pragma unroll
            for (int kj = 0; kj < 4; ++kj) {
                int rb = kj * 16 + llo;
                bf16x8 bk = *(const bf16x8*)((const char*)&Ks[cur][0]
                    + rb * 128 + (((ks * 4 + lhi) ^ (rb & 7)) << 4));
                sacc[kj] = MFMA16(bk, qf[ks], sacc[kj]);
            }
        }
        __builtin_amdgcn_s_setprio(0);

        const bool needMask = (kt == qt) || (win >= 0 && kt * 64 < q0 + 63 - winv);

        float sv[16];
        #pragma unroll
        for (int kj = 0; kj < 4; ++kj)
            #pragma unroll
            for (int r = 0; r < 4; ++r)
                sv[kj * 4 + r] = sacc[kj][r];
        if (needMask) {
            int qrowi = q0 + w * 16 + llo;
            #pragma unroll
            for (int kj = 0; kj < 4; ++kj)
                #pragma unroll
                for (int r = 0; r < 4; ++r) {
                    int key = kt * 64 + kj * 16 + lhi * 4 + r;
                    bool ok = (key <= qrowi) && (qrowi - key <= winv);
                    if (!ok) sv[kj * 4 + r] = -__builtin_inff();
                }
        }

        // fixed-max softmax: p = 2^(s - 12), no max bookkeeping
        float p[16], rs = 0.f;
        #pragma unroll
        for (int t = 0; t < 16; ++t) {
            p[t] = __builtin_amdgcn_exp2f(sv[t] - 12.0f);
            rs += p[t];
        }
        lrow += rs;

        // P -> per-wave swizzled LDS (row=llo, byte=key*2 ^ pswz)
        #pragma unroll
        for (int kj = 0; kj < 4; ++kj) {
            bf16x4 pk = { (__bf16)p[kj * 4 + 0], (__bf16)p[kj * 4 + 1],
                          (__bf16)p[kj * 4 + 2], (__bf16)p[kj * 4 + 3] };
            *(bf16x4*)((char*)&Ps[w][0]
                + ((llo * 128 + kj * 32 + lhi * 8) ^ pswz)) = pk;
        }

        // ---- O^T += V^T · P^T : D[d][q], q = llo ----
        __builtin_amdgcn_s_setprio(1);
        #pragma unroll
        for (int ks = 0; ks < 2; ++ks) {
            bf16x8 ap = *(const bf16x8*)((const char*)&Ps[w][0]
                + ((llo * 128 + ks * 64 + lhi * 16) ^ pswz));
            #pragma unroll
            for (int dj = 0; dj < 4; ++dj) {
                int rv = dj * 16 + llo;
                bf16x8 bv = *(const bf16x8*)((const char*)&VTs[cur][0]
                    + rv * 128 + (((ks * 4 + lhi) ^ (rv & 7)) << 4));
                oaccT[dj] = MFMA16(bv, ap, oaccT[dj]);
            }
        }
        __builtin_amdgcn_s_setprio(0);
        cur ^= 1;
    }

    // final cross-lane lrow reduction (once)
    lrow += __shfl_xor(lrow, 16, 64);
    lrow += __shfl_xor(lrow, 32, 64);

    float inv = 1.0f / lrow;
    int row = b * 2048 + q0 + w * 16 + llo;
    #pragma unroll
    for (int dj = 0; dj < 4; ++dj) {
        bf16x4 o = { (__bf16)(oaccT[dj][0] * inv), (__bf16)(oaccT[dj][1] * inv),
                     (__bf16)(oaccT[dj][2] * inv), (__bf16)(oaccT[dj][3] * inv) };
        *(bf16x4*)(&y[(size_t)row * 1024 + h * 64 + dj * 16 + lhi * 4]) = o;
    }
}

// ---------------------------------------------------------------------------
extern "C" void kernel_launch(void* const* d_in, const int* in_sizes, int n_in,
                              void* d_out, int out_size, void* d_ws, size_t ws_size,
                              hipStream_t stream) {
    const float* x     = (const float*)d_in[0];
    const float* ve    = (const float*)d_in[1];
    const float* cosb  = (const float*)d_in[2];
    const float* sinb  = (const float*)d_in[3];
    const float* Wq    = (const float*)d_in[4];
    const float* Wk    = (const float*)d_in[5];
    const float* Wv    = (const float*)d_in[6];
    const float* Wproj = (const float*)d_in[7];
    const float* Wg    = (const float*)d_in[8];
    const int*   winp  = (const int*)d_in[9];

    char* ws = (char*)d_ws;
    __bf16* qkv    = (__bf16*)(ws);                       // 16 MB  [4096][2048]
    __bf16* vT     = (__bf16*)(ws + (16u << 20));         //  4 MB  [2*8*64][2048]
    __bf16* ybuf   = (__bf16*)(ws + (20u << 20));         //  8 MB  [4096][1024]
    __bf16* xb     = (__bf16*)(ws + (28u << 20));         //  8 MB  [4096][1024]
    __bf16* wqkvt  = (__bf16*)(ws + (36u << 20));         //  4 MB  [2048][1024]
    __bf16* wprojt = (__bf16*)(ws + (40u << 20));         //  2 MB  [1024][1024]
    float*  gate   = (float*) (ws + (42u << 20));         // 128 KB [4096][8]

    prep_kernel<<<4224, 256, 0, stream>>>(x, xb, Wg, gate);
    tw_all<<<dim3(16, 16, 4), 256, 0, stream>>>(Wq, Wk, Wv, Wproj, wqkvt, wprojt);
    gemm_bf16<__bf16><<<dim3(16, 32), 256, 0, stream>>>(xb, wqkvt, qkv, 4096, 2048, 1024);
    post_kernel<<<25088, 256, 0, stream>>>(qkv, ve, gate, cosb, sinb, vT);
    attn_mfma<<<1024, 256, 0, stream>>>(qkv, vT, ybuf, winp);
    gemm_bf16<float><<<dim3(8, 32), 256, 0, stream>>>(ybuf, wprojt, (float*)d_out, 4096, 1024, 1024);
}